// Round 4
// baseline (338.323 us; speedup 1.0000x reference)
//
#include <hip/hip_runtime.h>

// ---------------------------------------------------------------------------
// CodecTransformerLayer on MI355X (gfx950).  fp32 inputs (sniff-confirmed),
// bf16 internal compute.  Round 4: attention rewritten — PV via two
// 16x16x16 f16 MFMAs so P is consumed in-place (zero cross-lane moves),
// V stored as f16 by the QKV epilogue, and 2-way key-split across waves
// (LDS merge) to double occupancy.
// B=2 S=2048 D=1024 H=16 KVH=8 hd=64 HIDDEN=4096 WINDOW=512
// ---------------------------------------------------------------------------

typedef __bf16 bf16;
typedef _Float16 f16;
typedef __attribute__((ext_vector_type(8))) __bf16 bf16x8;
typedef __attribute__((ext_vector_type(4))) _Float16 f16x4;
typedef __attribute__((ext_vector_type(4))) float f32x4;
typedef __attribute__((ext_vector_type(4))) short s16x4;

#define MFMA16(a, b, c) __builtin_amdgcn_mfma_f32_16x16x32_bf16(a, b, c, 0, 0, 0)
#define MFMAH(a, b, c)  __builtin_amdgcn_mfma_f32_16x16x16f16(a, b, c, 0, 0, 0)

__device__ __forceinline__ void gload_lds16(const bf16* g, bf16* l) {
    __builtin_amdgcn_global_load_lds(
        (const __attribute__((address_space(1))) unsigned int*)g,
        (__attribute__((address_space(3))) unsigned int*)l, 16, 0, 0);
}

// ---------------------------------------------------------------------------
// Dtype sniff: flag=1 means fp32 inputs.
// ---------------------------------------------------------------------------
__global__ void sniff_kernel(const unsigned short* __restrict__ x, int* __restrict__ flag) {
    __shared__ int s;
    if (threadIdx.x == 0) s = 0;
    __syncthreads();
    int bad = 0;
#pragma unroll
    for (int i = 0; i < 16; ++i) {
        const unsigned short u = x[threadIdx.x * 16 + i];
        const int e = (u >> 7) & 0xFF;
        if (e >= 135) bad = 1;
    }
    if (bad) atomicOr(&s, 1);
    __syncthreads();
    if (threadIdx.x == 0) flag[0] = s;
}

// ---------------------------------------------------------------------------
// Weight gather -> contiguous bf16 (convert when fp32, copy when bf16).
// seg map (elements): wq[0) wk[1048576) wv[1572864) wo[2097152) w1[3145728)
//                     w3[7340032) w2[11534336) end 15728640
// ---------------------------------------------------------------------------
__global__ void convert_all_kernel(const void* __restrict__ wq, const void* __restrict__ wk,
                                   const void* __restrict__ wv, const void* __restrict__ wo,
                                   const void* __restrict__ w1, const void* __restrict__ w3,
                                   const void* __restrict__ w2, bf16* __restrict__ dst,
                                   const int* __restrict__ flag) {
    const long e = ((long)blockIdx.x * 256 + threadIdx.x) * 4;
    const void* src; long off;
    if      (e < 1048576)  { src = wq; off = 0; }
    else if (e < 1572864)  { src = wk; off = 1048576; }
    else if (e < 2097152)  { src = wv; off = 1572864; }
    else if (e < 3145728)  { src = wo; off = 2097152; }
    else if (e < 7340032)  { src = w1; off = 3145728; }
    else if (e < 11534336) { src = w3; off = 7340032; }
    else                   { src = w2; off = 11534336; }
    if (flag[0] != 0) {
        const f32x4 v = *(const f32x4*)((const float*)src + (e - off));
        bf16 tmp[4];
#pragma unroll
        for (int j = 0; j < 4; ++j) tmp[j] = (bf16)v[j];
        *(s16x4*)(dst + e) = *(s16x4*)tmp;
    } else {
        *(s16x4*)(dst + e) = *(const s16x4*)((const short*)src + (e - off));
    }
}

// ---------------------------------------------------------------------------
// LayerNorm over last dim W (1024 or 512), one 128-thread block per row.
// ---------------------------------------------------------------------------
__global__ void ln_kernel(const void* __restrict__ in, const void* __restrict__ w,
                          bf16* __restrict__ out, int W, float eps,
                          const int* __restrict__ flag, int in_flv, int w_flv) {
    const int row = blockIdx.x, t = threadIdx.x;
    const int nch = W >> 3;
    const bool act = t < nch;
    const bool f32 = flag[0] != 0;
    float v[8];
    float s = 0.f, s2 = 0.f;
    if (act) {
        if (in_flv && f32) {
            const float* rp = (const float*)in + (size_t)row * W + t * 8;
            const f32x4 a = *(const f32x4*)rp, b = *(const f32x4*)(rp + 4);
#pragma unroll
            for (int j = 0; j < 4; ++j) { v[j] = a[j]; v[4 + j] = b[j]; }
        } else {
            const bf16x8 xv = *(const bf16x8*)((const bf16*)in + (size_t)row * W + t * 8);
#pragma unroll
            for (int j = 0; j < 8; ++j) v[j] = (float)xv[j];
        }
#pragma unroll
        for (int j = 0; j < 8; ++j) { s += v[j]; s2 += v[j] * v[j]; }
    }
#pragma unroll
    for (int off = 32; off; off >>= 1) { s += __shfl_xor(s, off); s2 += __shfl_xor(s2, off); }
    __shared__ float red[4];
    if ((t & 63) == 0) { red[(t >> 6) * 2] = s; red[(t >> 6) * 2 + 1] = s2; }
    __syncthreads();
    const float fs = red[0] + red[2], fs2 = red[1] + red[3];
    const float inw = 1.f / (float)W;
    const float mean = fs * inw;
    const float var = fs2 * inw - mean * mean;
    const float rstd = rsqrtf(var + eps);
    if (act) {
        float wv8[8];
        if (w_flv && f32) {
            const float* wp = (const float*)w + t * 8;
            const f32x4 a = *(const f32x4*)wp, b = *(const f32x4*)(wp + 4);
#pragma unroll
            for (int j = 0; j < 4; ++j) { wv8[j] = a[j]; wv8[4 + j] = b[j]; }
        } else {
            const bf16x8 ww = *(const bf16x8*)((const bf16*)w + t * 8);
#pragma unroll
            for (int j = 0; j < 8; ++j) wv8[j] = (float)ww[j];
        }
        bf16x8 ov;
#pragma unroll
        for (int j = 0; j < 8; ++j) ov[j] = (bf16)((v[j] - mean) * rstd * wv8[j]);
        *(bf16x8*)(out + (size_t)row * W + t * 8) = ov;
    }
}

// ---------------------------------------------------------------------------
// Pipelined GEMM  C[M,N] = A[M,K] * B[N,K]^T   (unchanged from round 3:
// 128x128 tile, BK=32, 8 waves, 3-buffer counted-vmcnt pipeline).
// Epilogues: 0 plain bf16; 1 res+acc*scale[col]; 3 silu(res)*acc;
//            4 fused QKV split (q bf16 | k bf16 | v-transposed F16).
// ---------------------------------------------------------------------------
template <int EPI>
__global__ __launch_bounds__(512, 4)
void gemm2(const bf16* __restrict__ A, const bf16* __restrict__ B,
           void* __restrict__ Cout, const void* __restrict__ res,
           const void* __restrict__ scale, int M, int N, int K,
           const int* __restrict__ flag, int res_flv, int out_flv) {
    __shared__ bf16 LDS[3 * 8192];
    const bool f32 = flag[0] != 0;
    const int t = threadIdx.x;
    const int wv = t >> 6, ln = t & 63;
    const int qr = ln & 15, g = ln >> 4;
    const int wr = wv >> 2, wc = wv & 3;
    const int row0 = blockIdx.y * 128, col0 = blockIdx.x * 128;

    f32x4 acc[4][2] = {};

    const bf16* aSrc = A + (size_t)(row0 + (t >> 2)) * K + (t & 3) * 8;
    const bf16* bSrc = B + (size_t)(col0 + (t >> 2)) * K + (t & 3) * 8;
    const int NIT = K >> 5;

#define STAGE(bi, k0)                                              \
    do {                                                           \
        bf16* lb = LDS + (bi) * 8192 + wv * 512;                   \
        gload_lds16(aSrc + (k0), lb);                              \
        gload_lds16(bSrc + (k0), lb + 4096);                       \
    } while (0)

    STAGE(0, 0);
    STAGE(1, 32);
    asm volatile("s_waitcnt vmcnt(2)" ::: "memory");
    __builtin_amdgcn_s_barrier();
    __builtin_amdgcn_sched_barrier(0);

    int cur = 0, sb = 2;
    for (int it = 0; it < NIT; ++it) {
        const bool more = (it + 2) < NIT;
        if (more) STAGE(sb, (it + 2) * 32);
        const bf16* bufA = LDS + cur * 8192;
        const bf16* bufB = bufA + 4096;
        bf16x8 af[4], bfr[2];
#pragma unroll
        for (int i = 0; i < 4; ++i)
            af[i] = *(const bf16x8*)&bufA[(wr * 64 + i * 16 + qr) * 32 + g * 8];
#pragma unroll
        for (int j = 0; j < 2; ++j)
            bfr[j] = *(const bf16x8*)&bufB[(wc * 32 + j * 16 + qr) * 32 + g * 8];
#pragma unroll
        for (int i = 0; i < 4; ++i)
#pragma unroll
            for (int j = 0; j < 2; ++j)
                acc[i][j] = MFMA16(af[i], bfr[j], acc[i][j]);
        if (more) asm volatile("s_waitcnt vmcnt(2)" ::: "memory");
        else      asm volatile("s_waitcnt vmcnt(0)" ::: "memory");
        __builtin_amdgcn_s_barrier();
        __builtin_amdgcn_sched_barrier(0);
        cur = cur == 2 ? 0 : cur + 1;
        sb  = sb  == 2 ? 0 : sb  + 1;
    }
#undef STAGE

#pragma unroll
    for (int i = 0; i < 4; ++i) {
#pragma unroll
        for (int j = 0; j < 2; ++j) {
            const int rr0 = row0 + wr * 64 + i * 16 + g * 4;  // C/D row=(l>>4)*4+r
            const int cc  = col0 + wc * 32 + j * 16 + qr;     //     col=l&15
            if (EPI == 4) {
                if (cc < 1024) {                 // q
#pragma unroll
                    for (int r = 0; r < 4; ++r)
                        ((bf16*)Cout)[(size_t)(rr0 + r) * 1024 + cc] = (bf16)acc[i][j][r];
                } else if (cc < 1536) {          // k
#pragma unroll
                    for (int r = 0; r < 4; ++r)
                        ((bf16*)res)[(size_t)(rr0 + r) * 512 + (cc - 1024)] = (bf16)acc[i][j][r];
                } else {                         // v transposed f16: Vt[b][kvh][d][s]
                    const int kv = cc - 1536, kvh = kv >> 6, d = kv & 63;
                    const int bb = rr0 >> 11, s0 = rr0 & 2047;
                    f16 tmp[4];
#pragma unroll
                    for (int r = 0; r < 4; ++r) tmp[r] = (f16)acc[i][j][r];
                    *(s16x4*)((f16*)scale + (((size_t)bb * 8 + kvh) * 64 + d) * 2048 + s0) = *(s16x4*)tmp;
                }
            } else {
                float scv = 0.f;
                if (EPI == 1)
                    scv = f32 ? ((const float*)scale)[cc] : (float)((const bf16*)scale)[cc];
#pragma unroll
                for (int r = 0; r < 4; ++r) {
                    const size_t idx = (size_t)(rr0 + r) * N + cc;
                    float vv = acc[i][j][r];
                    if (EPI == 1) {
                        const float rv = (res_flv && f32) ? ((const float*)res)[idx]
                                                          : (float)((const bf16*)res)[idx];
                        vv = rv + vv * scv;
                    }
                    if (EPI == 3) {
                        const float uv = (float)((const bf16*)res)[idx];
                        vv = uv / (1.f + __expf(-uv)) * vv;
                    }
                    if (out_flv && f32) ((float*)Cout)[idx] = vv;
                    else                ((bf16*)Cout)[idx] = (bf16)vv;
                }
            }
        }
    }
}

// ---------------------------------------------------------------------------
// Windowed-ALiBi GQA flash attention (key in [q, q+512]).
// Grid (S/32, H, B), 256 threads = 4 waves: 2 q-groups x 2 key-halves.
// Swapped QK^T (16x16x32 bf16): score at key = k16 + g*4 + r, q = lane&15 --
// which is EXACTLY the B-operand layout of v_mfma_f32_16x16x16_f16
// (k = g*4+j, col = lane&15), so PV consumes P in-place: zero shuffles.
// Key halves (9 + 8 tiles of 32) merge online-softmax states via LDS.
// ---------------------------------------------------------------------------
__global__ __launch_bounds__(256)
void attn_kernel(const bf16* __restrict__ qn, const bf16* __restrict__ kn,
                 const f16* __restrict__ vt, bf16* __restrict__ aout) {
    __shared__ float sm[2][64], sl[2][64], so[2][64][17];
    const int t = threadIdx.x, wv = t >> 6, ln = t & 63;
    const int qr = ln & 15, g = ln >> 4;
    const int qg = wv & 1, kh = wv >> 1;
    const int h = blockIdx.y, b = blockIdx.z, kvh = h >> 1;
    const int q0w = blockIdx.x * 32 + qg * 16;
    const int qa = q0w + qr;
    const float slope = exp2f(-0.5f * (float)(h + 1));

    const bf16* qrow = qn + ((size_t)(b * 2048 + qa)) * 1024 + h * 64;
    const bf16x8 qb0 = *(const bf16x8*)(qrow + g * 8);
    const bf16x8 qb1 = *(const bf16x8*)(qrow + 32 + g * 8);

    const bf16* kbase = kn + (size_t)b * 2048 * 512 + kvh * 64;
    const f16* vbase = vt + ((size_t)(b * 8 + kvh) * 64) * 2048;

    f32x4 o[4] = {};
    float mrun = -1e29f, lsum = 0.f;
    const int kstart = q0w + kh * 288;
    const int ntiles = kh ? 8 : 9;

    for (int it = 0; it < ntiles; ++it) {
        const int kt = kstart + it * 32;
        // ---- QK^T: S^T[key][q], key = kt + ks*16 + g*4 + r ------------------
        f32x4 sc[2] = {f32x4{0, 0, 0, 0}, f32x4{0, 0, 0, 0}};
#pragma unroll
        for (int ks = 0; ks < 2; ++ks) {
            int krow = kt + ks * 16 + qr;
            krow = krow > 2047 ? 2047 : krow;        // clamp; masked via P
            const bf16* kr = kbase + (size_t)krow * 512;
            sc[ks] = MFMA16(*(const bf16x8*)(kr + g * 8),      qb0, sc[ks]);
            sc[ks] = MFMA16(*(const bf16x8*)(kr + 32 + g * 8), qb1, sc[ks]);
        }
        // ---- mask + online softmax -----------------------------------------
        float s[2][4];
        float tmax = -1e30f;
#pragma unroll
        for (int ks = 0; ks < 2; ++ks)
#pragma unroll
            for (int r = 0; r < 4; ++r) {
                const int key = kt + ks * 16 + g * 4 + r;
                const int dist = key - qa;
                const bool valid = (dist >= 0) && (dist <= 512) && (key < 2048);
                const float sv = valid ? sc[ks][r] * 0.125f - slope * (float)dist : -1e30f;
                s[ks][r] = sv;
                tmax = fmaxf(tmax, sv);
            }
        tmax = fmaxf(tmax, __shfl_xor(tmax, 16));
        tmax = fmaxf(tmax, __shfl_xor(tmax, 32));
        const float mnew = fmaxf(mrun, tmax);
        const float alpha = __expf(mrun - mnew);
        mrun = mnew;
        f16x4 pf[2];
        float ps = 0.f;
#pragma unroll
        for (int ks = 0; ks < 2; ++ks)
#pragma unroll
            for (int r = 0; r < 4; ++r) {
                const float pv = __expf(s[ks][r] - mnew);
                ps += pv;
                pf[ks][r] = (f16)pv;
            }
        lsum = lsum * alpha + ps;
#pragma unroll
        for (int fd = 0; fd < 4; ++fd) o[fd] *= alpha;
        // ---- PV: out^T += Vt_frag(A) * P^T(B, in-place) ---------------------
#pragma unroll
        for (int fd = 0; fd < 4; ++fd)
#pragma unroll
            for (int ks = 0; ks < 2; ++ks) {
                int kbv = kt + ks * 16 + g * 4;
                kbv = kbv > 2044 ? 2044 : kbv;       // clamp; P=0 masks garbage
                const f16x4 va = *(const f16x4*)(vbase + (size_t)(fd * 16 + qr) * 2048 + kbv);
                o[fd] = MFMAH(va, pf[ks], o[fd]);
            }
    }

    // ---- merge the two key-halves via LDS ----------------------------------
    if (kh == 1) {
        sm[qg][ln] = mrun;
        sl[qg][ln] = lsum;
#pragma unroll
        for (int fd = 0; fd < 4; ++fd)
#pragma unroll
            for (int r = 0; r < 4; ++r) so[qg][ln][fd * 4 + r] = o[fd][r];
    }
    __syncthreads();
    if (kh == 0) {
        const float mB = sm[qg][ln], lB = sl[qg][ln];
        const float m = fmaxf(mrun, mB);
        const float aA = __expf(mrun - m), aB = __expf(mB - m);
        lsum = lsum * aA + lB * aB;
#pragma unroll
        for (int fd = 0; fd < 4; ++fd)
#pragma unroll
            for (int r = 0; r < 4; ++r)
                o[fd][r] = o[fd][r] * aA + so[qg][ln][fd * 4 + r] * aB;
        float lt = lsum + __shfl_xor(lsum, 16);
        lt += __shfl_xor(lt, 32);
        lt = fmaxf(lt, 1e-30f);
        const float inv = 1.f / lt;
        bf16* orow = aout + ((size_t)(b * 2048 + qa)) * 1024 + h * 64;
#pragma unroll
        for (int fd = 0; fd < 4; ++fd) {
            bf16 tmp[4];
#pragma unroll
            for (int r = 0; r < 4; ++r) tmp[r] = (bf16)(o[fd][r] * inv);
            *(s16x4*)(orow + fd * 16 + g * 4) = *(s16x4*)tmp;
        }
    }
}

// ---------------------------------------------------------------------------
extern "C" void kernel_launch(void* const* d_in, const int* in_sizes, int n_in,
                              void* d_out, int out_size, void* d_ws, size_t ws_size,
                              hipStream_t stream) {
    int* flag = (int*)d_ws;
    bf16* base = (bf16*)d_ws + 64;
    bf16* h    = base;                // 4096*1024  (reused as h2)
    bf16* q    = h + 4194304;         // 4096*1024  (reused as x1 after attn)
    bf16* kbuf = q + 4194304;         // 4096*512
    bf16* vtb  = kbuf + 2097152;      // 2*8*64*2048  (f16 elements)
    bf16* aout = vtb + 2097152;       // 4096*1024
    bf16* u    = aout + 4194304;      // 4096*4096  (reused as act)
    bf16* wcv  = u + 16777216;        // 15728640 converted weights (contiguous)

    bf16* woc = wcv + 2097152;
    bf16* w1c = wcv + 3145728;
    bf16* w3c = wcv + 7340032;
    bf16* w2c = wcv + 11534336;

    const dim3 blk(512);
    sniff_kernel<<<1, 256, 0, stream>>>((const unsigned short*)d_in[0], flag);
    convert_all_kernel<<<15360, 256, 0, stream>>>(
        d_in[1], d_in[2], d_in[3], d_in[4], d_in[9], d_in[11], d_in[10], wcv, flag);

    ln_kernel<<<4096, 128, 0, stream>>>(d_in[0], d_in[7], h, 1024, 1e-5f, flag, 1, 1);
    // fused QKV: B = [wq;wk;wv] rows, N=2048.  EPI4: Cout=q, res=kbuf, scale=vtb(f16)
    gemm2<4><<<dim3(16, 32), blk, 0, stream>>>(h, wcv, q, kbuf, vtb, 4096, 2048, 1024, flag, 0, 0);
    ln_kernel<<<4096, 128, 0, stream>>>(q, d_in[5], q, 1024, 1e-6f, flag, 0, 1);
    ln_kernel<<<4096, 128, 0, stream>>>(kbuf, d_in[6], kbuf, 512, 1e-6f, flag, 0, 1);
    attn_kernel<<<dim3(64, 16, 2), dim3(256), 0, stream>>>(q, kbuf, (const f16*)vtb, aout);
    // x1 = x + (aout@wo^T)*attn_scale  -> q (bf16)
    gemm2<1><<<dim3(8, 32), blk, 0, stream>>>(aout, woc, q, d_in[0], d_in[12], 4096, 1024, 1024, flag, 1, 0);
    ln_kernel<<<4096, 128, 0, stream>>>(q, d_in[8], h, 1024, 1e-5f, flag, 0, 1);
    gemm2<0><<<dim3(32, 32), blk, 0, stream>>>(h, w1c, u, nullptr, nullptr, 4096, 4096, 1024, flag, 0, 0);
    gemm2<3><<<dim3(32, 32), blk, 0, stream>>>(h, w3c, u, u, nullptr, 4096, 4096, 1024, flag, 0, 0);
    gemm2<1><<<dim3(8, 32), blk, 0, stream>>>(u, w2c, d_out, q, d_in[13], 4096, 1024, 4096, flag, 0, 1);
}

// Round 5
// 320.776 us; speedup vs baseline: 1.0547x; 1.0547x over previous
//
#include <hip/hip_runtime.h>

// ---------------------------------------------------------------------------
// CodecTransformerLayer on MI355X (gfx950).  fp32 inputs (sniff-confirmed),
// bf16 internal compute.  Round 5: attention = round-3 structure (verified
// 71.7us) + register double-buffer prefetch of next K/V tile (hides L2
// latency under softmax/PV).  GEMMs/LNs unchanged from round 3.
// B=2 S=2048 D=1024 H=16 KVH=8 hd=64 HIDDEN=4096 WINDOW=512
// ---------------------------------------------------------------------------

typedef __bf16 bf16;
typedef __attribute__((ext_vector_type(8))) __bf16 bf16x8;
typedef __attribute__((ext_vector_type(4))) float f32x4;
typedef __attribute__((ext_vector_type(4))) short s16x4;

#define MFMA16(a, b, c) __builtin_amdgcn_mfma_f32_16x16x32_bf16(a, b, c, 0, 0, 0)

__device__ __forceinline__ void gload_lds16(const bf16* g, bf16* l) {
    __builtin_amdgcn_global_load_lds(
        (const __attribute__((address_space(1))) unsigned int*)g,
        (__attribute__((address_space(3))) unsigned int*)l, 16, 0, 0);
}

// ---------------------------------------------------------------------------
// Dtype sniff: flag=1 means fp32 inputs.
// ---------------------------------------------------------------------------
__global__ void sniff_kernel(const unsigned short* __restrict__ x, int* __restrict__ flag) {
    __shared__ int s;
    if (threadIdx.x == 0) s = 0;
    __syncthreads();
    int bad = 0;
#pragma unroll
    for (int i = 0; i < 16; ++i) {
        const unsigned short u = x[threadIdx.x * 16 + i];
        const int e = (u >> 7) & 0xFF;
        if (e >= 135) bad = 1;
    }
    if (bad) atomicOr(&s, 1);
    __syncthreads();
    if (threadIdx.x == 0) flag[0] = s;
}

// ---------------------------------------------------------------------------
// Weight gather -> contiguous bf16 (convert when fp32, copy when bf16).
// seg map (elements): wq[0) wk[1048576) wv[1572864) wo[2097152) w1[3145728)
//                     w3[7340032) w2[11534336) end 15728640
// ---------------------------------------------------------------------------
__global__ void convert_all_kernel(const void* __restrict__ wq, const void* __restrict__ wk,
                                   const void* __restrict__ wv, const void* __restrict__ wo,
                                   const void* __restrict__ w1, const void* __restrict__ w3,
                                   const void* __restrict__ w2, bf16* __restrict__ dst,
                                   const int* __restrict__ flag) {
    const long e = ((long)blockIdx.x * 256 + threadIdx.x) * 4;
    const void* src; long off;
    if      (e < 1048576)  { src = wq; off = 0; }
    else if (e < 1572864)  { src = wk; off = 1048576; }
    else if (e < 2097152)  { src = wv; off = 1572864; }
    else if (e < 3145728)  { src = wo; off = 2097152; }
    else if (e < 7340032)  { src = w1; off = 3145728; }
    else if (e < 11534336) { src = w3; off = 7340032; }
    else                   { src = w2; off = 11534336; }
    if (flag[0] != 0) {
        const f32x4 v = *(const f32x4*)((const float*)src + (e - off));
        bf16 tmp[4];
#pragma unroll
        for (int j = 0; j < 4; ++j) tmp[j] = (bf16)v[j];
        *(s16x4*)(dst + e) = *(s16x4*)tmp;
    } else {
        *(s16x4*)(dst + e) = *(const s16x4*)((const short*)src + (e - off));
    }
}

// ---------------------------------------------------------------------------
// LayerNorm over last dim W (1024 or 512), one 128-thread block per row.
// ---------------------------------------------------------------------------
__global__ void ln_kernel(const void* __restrict__ in, const void* __restrict__ w,
                          bf16* __restrict__ out, int W, float eps,
                          const int* __restrict__ flag, int in_flv, int w_flv) {
    const int row = blockIdx.x, t = threadIdx.x;
    const int nch = W >> 3;
    const bool act = t < nch;
    const bool f32 = flag[0] != 0;
    float v[8];
    float s = 0.f, s2 = 0.f;
    if (act) {
        if (in_flv && f32) {
            const float* rp = (const float*)in + (size_t)row * W + t * 8;
            const f32x4 a = *(const f32x4*)rp, b = *(const f32x4*)(rp + 4);
#pragma unroll
            for (int j = 0; j < 4; ++j) { v[j] = a[j]; v[4 + j] = b[j]; }
        } else {
            const bf16x8 xv = *(const bf16x8*)((const bf16*)in + (size_t)row * W + t * 8);
#pragma unroll
            for (int j = 0; j < 8; ++j) v[j] = (float)xv[j];
        }
#pragma unroll
        for (int j = 0; j < 8; ++j) { s += v[j]; s2 += v[j] * v[j]; }
    }
#pragma unroll
    for (int off = 32; off; off >>= 1) { s += __shfl_xor(s, off); s2 += __shfl_xor(s2, off); }
    __shared__ float red[4];
    if ((t & 63) == 0) { red[(t >> 6) * 2] = s; red[(t >> 6) * 2 + 1] = s2; }
    __syncthreads();
    const float fs = red[0] + red[2], fs2 = red[1] + red[3];
    const float inw = 1.f / (float)W;
    const float mean = fs * inw;
    const float var = fs2 * inw - mean * mean;
    const float rstd = rsqrtf(var + eps);
    if (act) {
        float wv8[8];
        if (w_flv && f32) {
            const float* wp = (const float*)w + t * 8;
            const f32x4 a = *(const f32x4*)wp, b = *(const f32x4*)(wp + 4);
#pragma unroll
            for (int j = 0; j < 4; ++j) { wv8[j] = a[j]; wv8[4 + j] = b[j]; }
        } else {
            const bf16x8 ww = *(const bf16x8*)((const bf16*)w + t * 8);
#pragma unroll
            for (int j = 0; j < 8; ++j) wv8[j] = (float)ww[j];
        }
        bf16x8 ov;
#pragma unroll
        for (int j = 0; j < 8; ++j) ov[j] = (bf16)((v[j] - mean) * rstd * wv8[j]);
        *(bf16x8*)(out + (size_t)row * W + t * 8) = ov;
    }
}

// ---------------------------------------------------------------------------
// Pipelined GEMM  C[M,N] = A[M,K] * B[N,K]^T   (unchanged from round 3:
// 128x128 tile, BK=32, 8 waves, 3-buffer counted-vmcnt pipeline).
// Epilogues: 0 plain bf16; 1 res+acc*scale[col]; 3 silu(res)*acc;
//            4 fused QKV split (q bf16 | k bf16 | v-transposed bf16).
// ---------------------------------------------------------------------------
template <int EPI>
__global__ __launch_bounds__(512, 4)
void gemm2(const bf16* __restrict__ A, const bf16* __restrict__ B,
           void* __restrict__ Cout, const void* __restrict__ res,
           const void* __restrict__ scale, int M, int N, int K,
           const int* __restrict__ flag, int res_flv, int out_flv) {
    __shared__ bf16 LDS[3 * 8192];
    const bool f32 = flag[0] != 0;
    const int t = threadIdx.x;
    const int wv = t >> 6, ln = t & 63;
    const int qr = ln & 15, g = ln >> 4;
    const int wr = wv >> 2, wc = wv & 3;
    const int row0 = blockIdx.y * 128, col0 = blockIdx.x * 128;

    f32x4 acc[4][2] = {};

    const bf16* aSrc = A + (size_t)(row0 + (t >> 2)) * K + (t & 3) * 8;
    const bf16* bSrc = B + (size_t)(col0 + (t >> 2)) * K + (t & 3) * 8;
    const int NIT = K >> 5;

#define STAGE(bi, k0)                                              \
    do {                                                           \
        bf16* lb = LDS + (bi) * 8192 + wv * 512;                   \
        gload_lds16(aSrc + (k0), lb);                              \
        gload_lds16(bSrc + (k0), lb + 4096);                       \
    } while (0)

    STAGE(0, 0);
    STAGE(1, 32);
    asm volatile("s_waitcnt vmcnt(2)" ::: "memory");
    __builtin_amdgcn_s_barrier();
    __builtin_amdgcn_sched_barrier(0);

    int cur = 0, sb = 2;
    for (int it = 0; it < NIT; ++it) {
        const bool more = (it + 2) < NIT;
        if (more) STAGE(sb, (it + 2) * 32);
        const bf16* bufA = LDS + cur * 8192;
        const bf16* bufB = bufA + 4096;
        bf16x8 af[4], bfr[2];
#pragma unroll
        for (int i = 0; i < 4; ++i)
            af[i] = *(const bf16x8*)&bufA[(wr * 64 + i * 16 + qr) * 32 + g * 8];
#pragma unroll
        for (int j = 0; j < 2; ++j)
            bfr[j] = *(const bf16x8*)&bufB[(wc * 32 + j * 16 + qr) * 32 + g * 8];
#pragma unroll
        for (int i = 0; i < 4; ++i)
#pragma unroll
            for (int j = 0; j < 2; ++j)
                acc[i][j] = MFMA16(af[i], bfr[j], acc[i][j]);
        if (more) asm volatile("s_waitcnt vmcnt(2)" ::: "memory");
        else      asm volatile("s_waitcnt vmcnt(0)" ::: "memory");
        __builtin_amdgcn_s_barrier();
        __builtin_amdgcn_sched_barrier(0);
        cur = cur == 2 ? 0 : cur + 1;
        sb  = sb  == 2 ? 0 : sb  + 1;
    }
#undef STAGE

#pragma unroll
    for (int i = 0; i < 4; ++i) {
#pragma unroll
        for (int j = 0; j < 2; ++j) {
            const int rr0 = row0 + wr * 64 + i * 16 + g * 4;  // C/D row=(l>>4)*4+r
            const int cc  = col0 + wc * 32 + j * 16 + qr;     //     col=l&15
            if (EPI == 4) {
                if (cc < 1024) {                 // q
#pragma unroll
                    for (int r = 0; r < 4; ++r)
                        ((bf16*)Cout)[(size_t)(rr0 + r) * 1024 + cc] = (bf16)acc[i][j][r];
                } else if (cc < 1536) {          // k
#pragma unroll
                    for (int r = 0; r < 4; ++r)
                        ((bf16*)res)[(size_t)(rr0 + r) * 512 + (cc - 1024)] = (bf16)acc[i][j][r];
                } else {                         // v transposed bf16: Vt[b][kvh][d][s]
                    const int kv = cc - 1536, kvh = kv >> 6, d = kv & 63;
                    const int bb = rr0 >> 11, s0 = rr0 & 2047;
                    bf16 tmp[4];
#pragma unroll
                    for (int r = 0; r < 4; ++r) tmp[r] = (bf16)acc[i][j][r];
                    *(s16x4*)((bf16*)scale + (((size_t)bb * 8 + kvh) * 64 + d) * 2048 + s0) = *(s16x4*)tmp;
                }
            } else {
                float scv = 0.f;
                if (EPI == 1)
                    scv = f32 ? ((const float*)scale)[cc] : (float)((const bf16*)scale)[cc];
#pragma unroll
                for (int r = 0; r < 4; ++r) {
                    const size_t idx = (size_t)(rr0 + r) * N + cc;
                    float vv = acc[i][j][r];
                    if (EPI == 1) {
                        const float rv = (res_flv && f32) ? ((const float*)res)[idx]
                                                          : (float)((const bf16*)res)[idx];
                        vv = rv + vv * scv;
                    }
                    if (EPI == 3) {
                        const float uv = (float)((const bf16*)res)[idx];
                        vv = uv / (1.f + __expf(-uv)) * vv;
                    }
                    if (out_flv && f32) ((float*)Cout)[idx] = vv;
                    else                ((bf16*)Cout)[idx] = (bf16)vv;
                }
            }
        }
    }
}

// ---------------------------------------------------------------------------
// Windowed-ALiBi GQA flash attention (key in [q, q+512]).  Grid (S/64, H, B),
// 4 independent waves/block, wave = 16 queries over all 17 key-tiles.
// Swapped QK^T (S^T=mfma(K,Q)) so softmax state is lane-local; PV B-operand
// (P^T) built via __shfl.  NEW: register double-buffer prefetch — tile t+1's
// 4 K-loads + 4 V-loads issue at the top of iteration t, consumed at t+1
// (counted vmcnt, ~full tile of latency cover).
// ---------------------------------------------------------------------------
__global__ __launch_bounds__(256)
void attn_kernel(const bf16* __restrict__ qn, const bf16* __restrict__ kn,
                 const bf16* __restrict__ vt, bf16* __restrict__ aout) {
    const int t = threadIdx.x, wv = t >> 6, ln = t & 63;
    const int qr = ln & 15, g = ln >> 4;
    const int h = blockIdx.y, b = blockIdx.z, kvh = h >> 1;
    const int q0w = blockIdx.x * 64 + wv * 16;
    const int qa = q0w + qr;
    const float slope = exp2f(-0.5f * (float)(h + 1));

    const bf16* qrow = qn + ((size_t)(b * 2048 + qa)) * 1024 + h * 64;
    const bf16x8 qb0 = *(const bf16x8*)(qrow + g * 8);
    const bf16x8 qb1 = *(const bf16x8*)(qrow + 32 + g * 8);

    const bf16* kbase = kn + (size_t)b * 2048 * 512 + kvh * 64;
    const bf16* vbase = vt + ((size_t)(b * 8 + kvh) * 64) * 2048;

    // K fragment address (ks selects 16-key group, half selects hd 0..31/32..63)
    auto kaddr = [&](int kt, int ks, int half) -> const bf16* {
        int krow = kt + ks * 16 + qr;
        krow = krow > 2047 ? 2047 : krow;            // clamp; masked via P
        return kbase + (size_t)krow * 512 + half * 32 + g * 8;
    };
    auto vaddr = [&](int kt, int fd) -> const bf16* {
        int kbv = kt + g * 8;
        kbv = kbv > 2040 ? 2040 : kbv;               // clamp; P=0 masks garbage
        return vbase + (size_t)(fd * 16 + qr) * 2048 + kbv;
    };

    f32x4 o[4] = {};
    float mrun = -1e29f, lsum = 0.f;

    // prologue: prefetch tile 0
    bf16x8 kN[4], vN[4];
#pragma unroll
    for (int ks = 0; ks < 2; ++ks)
#pragma unroll
        for (int half = 0; half < 2; ++half)
            kN[ks * 2 + half] = *(const bf16x8*)kaddr(q0w, ks, half);
#pragma unroll
    for (int fd = 0; fd < 4; ++fd) vN[fd] = *(const bf16x8*)vaddr(q0w, fd);

    for (int it = 0; it < 17; ++it) {
        const int kt = q0w + it * 32;
        // consume-copies (register renames) then issue next tile's loads
        bf16x8 kC[4], vC[4];
#pragma unroll
        for (int r = 0; r < 4; ++r) { kC[r] = kN[r]; vC[r] = vN[r]; }
        const int itn = it + 1 > 16 ? 16 : it + 1;   // last iter reloads same tile
        const int ktn = q0w + itn * 32;
#pragma unroll
        for (int ks = 0; ks < 2; ++ks)
#pragma unroll
            for (int half = 0; half < 2; ++half)
                kN[ks * 2 + half] = *(const bf16x8*)kaddr(ktn, ks, half);
#pragma unroll
        for (int fd = 0; fd < 4; ++fd) vN[fd] = *(const bf16x8*)vaddr(ktn, fd);

        // ---- QK^T: S^T[key][q], key = kt + ks*16 + g*4 + r -----------------
        f32x4 sc[2] = {f32x4{0, 0, 0, 0}, f32x4{0, 0, 0, 0}};
#pragma unroll
        for (int ks = 0; ks < 2; ++ks) {
            sc[ks] = MFMA16(kC[ks * 2 + 0], qb0, sc[ks]);
            sc[ks] = MFMA16(kC[ks * 2 + 1], qb1, sc[ks]);
        }
        // ---- mask + online softmax -----------------------------------------
        float s[2][4], p[2][4];
        float tmax = -1e30f;
#pragma unroll
        for (int ks = 0; ks < 2; ++ks)
#pragma unroll
            for (int r = 0; r < 4; ++r) {
                const int key = kt + ks * 16 + g * 4 + r;
                const int dist = key - qa;
                const bool valid = (dist >= 0) && (dist <= 512) && (key < 2048);
                const float sv = valid ? sc[ks][r] * 0.125f - slope * (float)dist : -1e30f;
                s[ks][r] = sv;
                tmax = fmaxf(tmax, sv);
            }
        tmax = fmaxf(tmax, __shfl_xor(tmax, 16));
        tmax = fmaxf(tmax, __shfl_xor(tmax, 32));
        const float mnew = fmaxf(mrun, tmax);
        const float alpha = __expf(mrun - mnew);
        mrun = mnew;
        float ps = 0.f;
#pragma unroll
        for (int ks = 0; ks < 2; ++ks)
#pragma unroll
            for (int r = 0; r < 4; ++r) { p[ks][r] = __expf(s[ks][r] - mnew); ps += p[ks][r]; }
        lsum = lsum * alpha + ps;
#pragma unroll
        for (int fd = 0; fd < 4; ++fd) o[fd] *= alpha;

        // ---- build PV B-operand: lane needs P^T[key=8g+j][q=qr], j=0..7 ----
        bf16x8 pb;
#pragma unroll
        for (int j = 0; j < 8; ++j) {
            const int srcl = (((2 * g + (j >> 2)) & 3) << 4) | qr;
            const float v0 = __shfl(p[0][j & 3], srcl);
            const float v1 = __shfl(p[1][j & 3], srcl);
            pb[j] = (bf16)((g & 2) ? v1 : v0);
        }
        // ---- PV: out^T += Vt_frag * P^T ------------------------------------
#pragma unroll
        for (int fd = 0; fd < 4; ++fd)
            o[fd] = MFMA16(vC[fd], pb, o[fd]);
    }
    float lt = lsum + __shfl_xor(lsum, 16);
    lt += __shfl_xor(lt, 32);
    lt = fmaxf(lt, 1e-30f);
    const float inv = 1.f / lt;
    bf16* orow = aout + ((size_t)(b * 2048 + qa)) * 1024 + h * 64;
#pragma unroll
    for (int fd = 0; fd < 4; ++fd) {
        bf16 tmp[4];
#pragma unroll
        for (int r = 0; r < 4; ++r) tmp[r] = (bf16)(o[fd][r] * inv);
        *(s16x4*)(orow + fd * 16 + g * 4) = *(s16x4*)tmp;
    }
}

// ---------------------------------------------------------------------------
extern "C" void kernel_launch(void* const* d_in, const int* in_sizes, int n_in,
                              void* d_out, int out_size, void* d_ws, size_t ws_size,
                              hipStream_t stream) {
    int* flag = (int*)d_ws;
    bf16* base = (bf16*)d_ws + 64;
    bf16* h    = base;                // 4096*1024  (reused as h2)
    bf16* q    = h + 4194304;         // 4096*1024  (reused as x1 after attn)
    bf16* kbuf = q + 4194304;         // 4096*512
    bf16* vtb  = kbuf + 2097152;      // 2*8*64*2048
    bf16* aout = vtb + 2097152;       // 4096*1024
    bf16* u    = aout + 4194304;      // 4096*4096  (reused as act)
    bf16* wcv  = u + 16777216;        // 15728640 converted weights (contiguous)

    bf16* woc = wcv + 2097152;
    bf16* w1c = wcv + 3145728;
    bf16* w3c = wcv + 7340032;
    bf16* w2c = wcv + 11534336;

    const dim3 blk(512);
    sniff_kernel<<<1, 256, 0, stream>>>((const unsigned short*)d_in[0], flag);
    convert_all_kernel<<<15360, 256, 0, stream>>>(
        d_in[1], d_in[2], d_in[3], d_in[4], d_in[9], d_in[11], d_in[10], wcv, flag);

    ln_kernel<<<4096, 128, 0, stream>>>(d_in[0], d_in[7], h, 1024, 1e-5f, flag, 1, 1);
    // fused QKV: B = [wq;wk;wv] rows, N=2048.  EPI4: Cout=q, res=kbuf, scale=vtb
    gemm2<4><<<dim3(16, 32), blk, 0, stream>>>(h, wcv, q, kbuf, vtb, 4096, 2048, 1024, flag, 0, 0);
    ln_kernel<<<4096, 128, 0, stream>>>(q, d_in[5], q, 1024, 1e-6f, flag, 0, 1);
    ln_kernel<<<4096, 128, 0, stream>>>(kbuf, d_in[6], kbuf, 512, 1e-6f, flag, 0, 1);
    attn_kernel<<<dim3(32, 16, 2), dim3(256), 0, stream>>>(q, kbuf, vtb, aout);
    // x1 = x + (aout@wo^T)*attn_scale  -> q (bf16)
    gemm2<1><<<dim3(8, 32), blk, 0, stream>>>(aout, woc, q, d_in[0], d_in[12], 4096, 1024, 1024, flag, 1, 0);
    ln_kernel<<<4096, 128, 0, stream>>>(q, d_in[8], h, 1024, 1e-5f, flag, 0, 1);
    gemm2<0><<<dim3(32, 32), blk, 0, stream>>>(h, w1c, u, nullptr, nullptr, 4096, 4096, 1024, flag, 0, 0);
    gemm2<3><<<dim3(32, 32), blk, 0, stream>>>(h, w3c, u, u, nullptr, 4096, 4096, 1024, flag, 0, 0);
    gemm2<1><<<dim3(8, 32), blk, 0, stream>>>(u, w2c, d_out, q, d_in[13], 4096, 1024, 4096, flag, 0, 1);
}

// Round 6
// 283.759 us; speedup vs baseline: 1.1923x; 1.1305x over previous
//
#include <hip/hip_runtime.h>

// ---------------------------------------------------------------------------
// CodecTransformerLayer on MI355X (gfx950).  fp32 inputs (sniff-confirmed),
// bf16 internal compute.  Round 6: attention adopts the gemm2-proven
// 3-buffer counted-vmcnt LDS pipeline for K/V tiles (block-shared staging,
// global_load_lds, T2 swizzle on K); compute body identical to round 3.
// GEMMs/LNs unchanged.
// B=2 S=2048 D=1024 H=16 KVH=8 hd=64 HIDDEN=4096 WINDOW=512
// ---------------------------------------------------------------------------

typedef __bf16 bf16;
typedef __attribute__((ext_vector_type(8))) __bf16 bf16x8;
typedef __attribute__((ext_vector_type(4))) float f32x4;
typedef __attribute__((ext_vector_type(4))) short s16x4;

#define MFMA16(a, b, c) __builtin_amdgcn_mfma_f32_16x16x32_bf16(a, b, c, 0, 0, 0)

__device__ __forceinline__ void gload_lds16(const bf16* g, bf16* l) {
    __builtin_amdgcn_global_load_lds(
        (const __attribute__((address_space(1))) unsigned int*)g,
        (__attribute__((address_space(3))) unsigned int*)l, 16, 0, 0);
}

// ---------------------------------------------------------------------------
// Dtype sniff: flag=1 means fp32 inputs.
// ---------------------------------------------------------------------------
__global__ void sniff_kernel(const unsigned short* __restrict__ x, int* __restrict__ flag) {
    __shared__ int s;
    if (threadIdx.x == 0) s = 0;
    __syncthreads();
    int bad = 0;
#pragma unroll
    for (int i = 0; i < 16; ++i) {
        const unsigned short u = x[threadIdx.x * 16 + i];
        const int e = (u >> 7) & 0xFF;
        if (e >= 135) bad = 1;
    }
    if (bad) atomicOr(&s, 1);
    __syncthreads();
    if (threadIdx.x == 0) flag[0] = s;
}

// ---------------------------------------------------------------------------
// Weight gather -> contiguous bf16 (convert when fp32, copy when bf16).
// ---------------------------------------------------------------------------
__global__ void convert_all_kernel(const void* __restrict__ wq, const void* __restrict__ wk,
                                   const void* __restrict__ wv, const void* __restrict__ wo,
                                   const void* __restrict__ w1, const void* __restrict__ w3,
                                   const void* __restrict__ w2, bf16* __restrict__ dst,
                                   const int* __restrict__ flag) {
    const long e = ((long)blockIdx.x * 256 + threadIdx.x) * 4;
    const void* src; long off;
    if      (e < 1048576)  { src = wq; off = 0; }
    else if (e < 1572864)  { src = wk; off = 1048576; }
    else if (e < 2097152)  { src = wv; off = 1572864; }
    else if (e < 3145728)  { src = wo; off = 2097152; }
    else if (e < 7340032)  { src = w1; off = 3145728; }
    else if (e < 11534336) { src = w3; off = 7340032; }
    else                   { src = w2; off = 11534336; }
    if (flag[0] != 0) {
        const f32x4 v = *(const f32x4*)((const float*)src + (e - off));
        bf16 tmp[4];
#pragma unroll
        for (int j = 0; j < 4; ++j) tmp[j] = (bf16)v[j];
        *(s16x4*)(dst + e) = *(s16x4*)tmp;
    } else {
        *(s16x4*)(dst + e) = *(const s16x4*)((const short*)src + (e - off));
    }
}

// ---------------------------------------------------------------------------
// LayerNorm over last dim W (1024 or 512), one 128-thread block per row.
// ---------------------------------------------------------------------------
__global__ void ln_kernel(const void* __restrict__ in, const void* __restrict__ w,
                          bf16* __restrict__ out, int W, float eps,
                          const int* __restrict__ flag, int in_flv, int w_flv) {
    const int row = blockIdx.x, t = threadIdx.x;
    const int nch = W >> 3;
    const bool act = t < nch;
    const bool f32 = flag[0] != 0;
    float v[8];
    float s = 0.f, s2 = 0.f;
    if (act) {
        if (in_flv && f32) {
            const float* rp = (const float*)in + (size_t)row * W + t * 8;
            const f32x4 a = *(const f32x4*)rp, b = *(const f32x4*)(rp + 4);
#pragma unroll
            for (int j = 0; j < 4; ++j) { v[j] = a[j]; v[4 + j] = b[j]; }
        } else {
            const bf16x8 xv = *(const bf16x8*)((const bf16*)in + (size_t)row * W + t * 8);
#pragma unroll
            for (int j = 0; j < 8; ++j) v[j] = (float)xv[j];
        }
#pragma unroll
        for (int j = 0; j < 8; ++j) { s += v[j]; s2 += v[j] * v[j]; }
    }
#pragma unroll
    for (int off = 32; off; off >>= 1) { s += __shfl_xor(s, off); s2 += __shfl_xor(s2, off); }
    __shared__ float red[4];
    if ((t & 63) == 0) { red[(t >> 6) * 2] = s; red[(t >> 6) * 2 + 1] = s2; }
    __syncthreads();
    const float fs = red[0] + red[2], fs2 = red[1] + red[3];
    const float inw = 1.f / (float)W;
    const float mean = fs * inw;
    const float var = fs2 * inw - mean * mean;
    const float rstd = rsqrtf(var + eps);
    if (act) {
        float wv8[8];
        if (w_flv && f32) {
            const float* wp = (const float*)w + t * 8;
            const f32x4 a = *(const f32x4*)wp, b = *(const f32x4*)(wp + 4);
#pragma unroll
            for (int j = 0; j < 4; ++j) { wv8[j] = a[j]; wv8[4 + j] = b[j]; }
        } else {
            const bf16x8 ww = *(const bf16x8*)((const bf16*)w + t * 8);
#pragma unroll
            for (int j = 0; j < 8; ++j) wv8[j] = (float)ww[j];
        }
        bf16x8 ov;
#pragma unroll
        for (int j = 0; j < 8; ++j) ov[j] = (bf16)((v[j] - mean) * rstd * wv8[j]);
        *(bf16x8*)(out + (size_t)row * W + t * 8) = ov;
    }
}

// ---------------------------------------------------------------------------
// Pipelined GEMM  C[M,N] = A[M,K] * B[N,K]^T   (unchanged from round 3).
// ---------------------------------------------------------------------------
template <int EPI>
__global__ __launch_bounds__(512, 4)
void gemm2(const bf16* __restrict__ A, const bf16* __restrict__ B,
           void* __restrict__ Cout, const void* __restrict__ res,
           const void* __restrict__ scale, int M, int N, int K,
           const int* __restrict__ flag, int res_flv, int out_flv) {
    __shared__ bf16 LDS[3 * 8192];
    const bool f32 = flag[0] != 0;
    const int t = threadIdx.x;
    const int wv = t >> 6, ln = t & 63;
    const int qr = ln & 15, g = ln >> 4;
    const int wr = wv >> 2, wc = wv & 3;
    const int row0 = blockIdx.y * 128, col0 = blockIdx.x * 128;

    f32x4 acc[4][2] = {};

    const bf16* aSrc = A + (size_t)(row0 + (t >> 2)) * K + (t & 3) * 8;
    const bf16* bSrc = B + (size_t)(col0 + (t >> 2)) * K + (t & 3) * 8;
    const int NIT = K >> 5;

#define STAGE(bi, k0)                                              \
    do {                                                           \
        bf16* lb = LDS + (bi) * 8192 + wv * 512;                   \
        gload_lds16(aSrc + (k0), lb);                              \
        gload_lds16(bSrc + (k0), lb + 4096);                       \
    } while (0)

    STAGE(0, 0);
    STAGE(1, 32);
    asm volatile("s_waitcnt vmcnt(2)" ::: "memory");
    __builtin_amdgcn_s_barrier();
    __builtin_amdgcn_sched_barrier(0);

    int cur = 0, sb = 2;
    for (int it = 0; it < NIT; ++it) {
        const bool more = (it + 2) < NIT;
        if (more) STAGE(sb, (it + 2) * 32);
        const bf16* bufA = LDS + cur * 8192;
        const bf16* bufB = bufA + 4096;
        bf16x8 af[4], bfr[2];
#pragma unroll
        for (int i = 0; i < 4; ++i)
            af[i] = *(const bf16x8*)&bufA[(wr * 64 + i * 16 + qr) * 32 + g * 8];
#pragma unroll
        for (int j = 0; j < 2; ++j)
            bfr[j] = *(const bf16x8*)&bufB[(wc * 32 + j * 16 + qr) * 32 + g * 8];
#pragma unroll
        for (int i = 0; i < 4; ++i)
#pragma unroll
            for (int j = 0; j < 2; ++j)
                acc[i][j] = MFMA16(af[i], bfr[j], acc[i][j]);
        if (more) asm volatile("s_waitcnt vmcnt(2)" ::: "memory");
        else      asm volatile("s_waitcnt vmcnt(0)" ::: "memory");
        __builtin_amdgcn_s_barrier();
        __builtin_amdgcn_sched_barrier(0);
        cur = cur == 2 ? 0 : cur + 1;
        sb  = sb  == 2 ? 0 : sb  + 1;
    }
#undef STAGE

#pragma unroll
    for (int i = 0; i < 4; ++i) {
#pragma unroll
        for (int j = 0; j < 2; ++j) {
            const int rr0 = row0 + wr * 64 + i * 16 + g * 4;  // C/D row=(l>>4)*4+r
            const int cc  = col0 + wc * 32 + j * 16 + qr;     //     col=l&15
            if (EPI == 4) {
                if (cc < 1024) {                 // q
#pragma unroll
                    for (int r = 0; r < 4; ++r)
                        ((bf16*)Cout)[(size_t)(rr0 + r) * 1024 + cc] = (bf16)acc[i][j][r];
                } else if (cc < 1536) {          // k
#pragma unroll
                    for (int r = 0; r < 4; ++r)
                        ((bf16*)res)[(size_t)(rr0 + r) * 512 + (cc - 1024)] = (bf16)acc[i][j][r];
                } else {                         // v transposed bf16: Vt[b][kvh][d][s]
                    const int kv = cc - 1536, kvh = kv >> 6, d = kv & 63;
                    const int bb = rr0 >> 11, s0 = rr0 & 2047;
                    bf16 tmp[4];
#pragma unroll
                    for (int r = 0; r < 4; ++r) tmp[r] = (bf16)acc[i][j][r];
                    *(s16x4*)((bf16*)scale + (((size_t)bb * 8 + kvh) * 64 + d) * 2048 + s0) = *(s16x4*)tmp;
                }
            } else {
                float scv = 0.f;
                if (EPI == 1)
                    scv = f32 ? ((const float*)scale)[cc] : (float)((const bf16*)scale)[cc];
#pragma unroll
                for (int r = 0; r < 4; ++r) {
                    const size_t idx = (size_t)(rr0 + r) * N + cc;
                    float vv = acc[i][j][r];
                    if (EPI == 1) {
                        const float rv = (res_flv && f32) ? ((const float*)res)[idx]
                                                          : (float)((const bf16*)res)[idx];
                        vv = rv + vv * scv;
                    }
                    if (EPI == 3) {
                        const float uv = (float)((const bf16*)res)[idx];
                        vv = uv / (1.f + __expf(-uv)) * vv;
                    }
                    if (out_flv && f32) ((float*)Cout)[idx] = vv;
                    else                ((bf16*)Cout)[idx] = (bf16)vv;
                }
            }
        }
    }
}

// ---------------------------------------------------------------------------
// Windowed-ALiBi GQA flash attention (key in [q, q+512]).  Grid (S/64, H, B),
// 256 threads = 4 waves at q0blk + wv*16; all waves iterate the block's 18
// shared key-tiles [q0blk, q0blk+576) staged through LDS:
//   3 buffers x (K 4KB + V 4KB), 1 global_load_lds each for K and V per tile,
//   depth-2 prefetch, counted vmcnt(4) (gemm2's proven ledger).
// K tiles T2-swizzled (128B rows, 2-way = free); V tiles 64B rows (residual
// 8-way accepted).  OOB key rows clamped at staging (finite data; P=0 masks).
// Compute body identical to round 3 (verified 71.7us).
// ---------------------------------------------------------------------------
__global__ __launch_bounds__(256)
void attn_kernel(const bf16* __restrict__ qn, const bf16* __restrict__ kn,
                 const bf16* __restrict__ vt, bf16* __restrict__ aout) {
    __shared__ bf16 SH[3 * 4096];      // buf: K [32 key][64 hd] | V [64 d][32 key]
    const int t = threadIdx.x, wv = t >> 6, ln = t & 63;
    const int qr = ln & 15, g = ln >> 4;
    const int h = blockIdx.y, b = blockIdx.z, kvh = h >> 1;
    const int q0blk = blockIdx.x * 64;
    const int qa = q0blk + wv * 16 + qr;
    const float slope = exp2f(-0.5f * (float)(h + 1));

    const bf16* qrow = qn + ((size_t)(b * 2048 + qa)) * 1024 + h * 64;
    const bf16x8 qb0 = *(const bf16x8*)(qrow + g * 8);
    const bf16x8 qb1 = *(const bf16x8*)(qrow + 32 + g * 8);

    // ---- staging geometry (thread-constant) --------------------------------
    const bf16* kbase = kn + (size_t)b * 2048 * 512 + kvh * 64;
    const bf16* vbase = vt + ((size_t)(b * 8 + kvh) * 64) * 2048;
    const int krow_l = t >> 3;                       // 0..31 local key row
    const int kcsrc  = (t & 7) ^ ((t >> 3) & 7);     // swizzled K chunk
    const int vd     = t >> 2;                       // 0..63 local d row
    const int vcsrc  = (t & 3) ^ ((t >> 2) & 3);     // swizzled V chunk
    const bf16* kgsrc = kbase + kcsrc * 8;           // + keyrow*512
    const bf16* vgsrc = vbase + (size_t)vd * 2048;   // + keychunk
    bf16* lK0 = SH + wv * 512;                       // wave-uniform dests
    bf16* lV0 = SH + 2048 + wv * 512;

#define STAGE_T(kts, bi)                                           \
    do {                                                           \
        int ksrc = (kts) + krow_l;                                 \
        ksrc = ksrc > 2047 ? 2047 : ksrc;                          \
        gload_lds16(kgsrc + (size_t)ksrc * 512, lK0 + (bi) * 4096);\
        int vsrc = (kts) + vcsrc * 8;                              \
        vsrc = vsrc > 2040 ? 2040 : vsrc;                          \
        gload_lds16(vgsrc + vsrc, lV0 + (bi) * 4096);              \
    } while (0)

    STAGE_T(q0blk, 0);
    STAGE_T(q0blk + 32, 1);
    STAGE_T(q0blk + 64, 2);
    asm volatile("s_waitcnt vmcnt(4)" ::: "memory");
    __builtin_amdgcn_s_barrier();
    __builtin_amdgcn_sched_barrier(0);

    f32x4 o[4] = {};
    float mrun = -1e29f, lsum = 0.f;
    int cur = 0;

    for (int it = 0; it < 18; ++it) {
        const int kt = q0blk + it * 32;
        const bf16* Kb = SH + cur * 4096;
        const bf16* Vb = Kb + 2048;

        // ---- QK^T: S^T[key][q], key = kt + ks*16 + g*4 + r -----------------
        f32x4 sc[2] = {f32x4{0, 0, 0, 0}, f32x4{0, 0, 0, 0}};
#pragma unroll
        for (int ks = 0; ks < 2; ++ks) {
            const int lrow = ks * 16 + qr;
            const int sw = (lrow & 7) * 8;
            sc[ks] = MFMA16(*(const bf16x8*)&Kb[lrow * 64 + (((g) * 8) ^ sw)],        qb0, sc[ks]);
            sc[ks] = MFMA16(*(const bf16x8*)&Kb[lrow * 64 + (((4 + g) * 8) ^ sw)],    qb1, sc[ks]);
        }
        // ---- mask + online softmax -----------------------------------------
        float s[2][4], p[2][4];
        float tmax = -1e30f;
#pragma unroll
        for (int ks = 0; ks < 2; ++ks)
#pragma unroll
            for (int r = 0; r < 4; ++r) {
                const int key = kt + ks * 16 + g * 4 + r;
                const int dist = key - qa;
                const bool valid = (dist >= 0) && (dist <= 512) && (key < 2048);
                const float sv = valid ? sc[ks][r] * 0.125f - slope * (float)dist : -1e30f;
                s[ks][r] = sv;
                tmax = fmaxf(tmax, sv);
            }
        tmax = fmaxf(tmax, __shfl_xor(tmax, 16));
        tmax = fmaxf(tmax, __shfl_xor(tmax, 32));
        const float mnew = fmaxf(mrun, tmax);
        const float alpha = __expf(mrun - mnew);
        mrun = mnew;
        float ps = 0.f;
#pragma unroll
        for (int ks = 0; ks < 2; ++ks)
#pragma unroll
            for (int r = 0; r < 4; ++r) { p[ks][r] = __expf(s[ks][r] - mnew); ps += p[ks][r]; }
        lsum = lsum * alpha + ps;
#pragma unroll
        for (int fd = 0; fd < 4; ++fd) o[fd] *= alpha;

        // ---- build PV B-operand: lane needs P^T[key=8g+j][q=qr], j=0..7 ----
        bf16x8 pb;
#pragma unroll
        for (int j = 0; j < 8; ++j) {
            const int srcl = (((2 * g + (j >> 2)) & 3) << 4) | qr;
            const float v0 = __shfl(p[0][j & 3], srcl);
            const float v1 = __shfl(p[1][j & 3], srcl);
            pb[j] = (bf16)((g & 2) ? v1 : v0);
        }
        // ---- PV: out^T += Vt_frag * P^T  (V from LDS, swizzled 4-chunk) ----
#pragma unroll
        for (int fd = 0; fd < 4; ++fd) {
            const int d = fd * 16 + qr;
            const bf16x8 va = *(const bf16x8*)&Vb[d * 32 + ((g ^ (d & 3)) * 8)];
            o[fd] = MFMA16(va, pb, o[fd]);
        }

        // ---- pipeline maintenance ------------------------------------------
        __builtin_amdgcn_s_barrier();                 // all waves done with buf cur
        if (it + 3 < 18) {
            STAGE_T(kt + 96, cur);
            asm volatile("s_waitcnt vmcnt(4)" ::: "memory");
        } else {
            asm volatile("s_waitcnt vmcnt(0)" ::: "memory");
        }
        __builtin_amdgcn_s_barrier();                 // publish buf for tile it+1
        __builtin_amdgcn_sched_barrier(0);
        cur = cur == 2 ? 0 : cur + 1;
    }
#undef STAGE_T

    float lt = lsum + __shfl_xor(lsum, 16);
    lt += __shfl_xor(lt, 32);
    lt = fmaxf(lt, 1e-30f);
    const float inv = 1.f / lt;
    bf16* orow = aout + ((size_t)(b * 2048 + qa)) * 1024 + h * 64;
#pragma unroll
    for (int fd = 0; fd < 4; ++fd) {
        bf16 tmp[4];
#pragma unroll
        for (int r = 0; r < 4; ++r) tmp[r] = (bf16)(o[fd][r] * inv);
        *(s16x4*)(orow + fd * 16 + g * 4) = *(s16x4*)tmp;
    }
}

// ---------------------------------------------------------------------------
extern "C" void kernel_launch(void* const* d_in, const int* in_sizes, int n_in,
                              void* d_out, int out_size, void* d_ws, size_t ws_size,
                              hipStream_t stream) {
    int* flag = (int*)d_ws;
    bf16* base = (bf16*)d_ws + 64;
    bf16* h    = base;                // 4096*1024  (reused as h2)
    bf16* q    = h + 4194304;         // 4096*1024  (reused as x1 after attn)
    bf16* kbuf = q + 4194304;         // 4096*512
    bf16* vtb  = kbuf + 2097152;      // 2*8*64*2048
    bf16* aout = vtb + 2097152;       // 4096*1024
    bf16* u    = aout + 4194304;      // 4096*4096  (reused as act)
    bf16* wcv  = u + 16777216;        // 15728640 converted weights (contiguous)

    bf16* woc = wcv + 2097152;
    bf16* w1c = wcv + 3145728;
    bf16* w3c = wcv + 7340032;
    bf16* w2c = wcv + 11534336;

    const dim3 blk(512);
    sniff_kernel<<<1, 256, 0, stream>>>((const unsigned short*)d_in[0], flag);
    convert_all_kernel<<<15360, 256, 0, stream>>>(
        d_in[1], d_in[2], d_in[3], d_in[4], d_in[9], d_in[11], d_in[10], wcv, flag);

    ln_kernel<<<4096, 128, 0, stream>>>(d_in[0], d_in[7], h, 1024, 1e-5f, flag, 1, 1);
    // fused QKV: B = [wq;wk;wv] rows, N=2048.  EPI4: Cout=q, res=kbuf, scale=vtb
    gemm2<4><<<dim3(16, 32), blk, 0, stream>>>(h, wcv, q, kbuf, vtb, 4096, 2048, 1024, flag, 0, 0);
    ln_kernel<<<4096, 128, 0, stream>>>(q, d_in[5], q, 1024, 1e-6f, flag, 0, 1);
    ln_kernel<<<4096, 128, 0, stream>>>(kbuf, d_in[6], kbuf, 512, 1e-6f, flag, 0, 1);
    attn_kernel<<<dim3(32, 16, 2), dim3(256), 0, stream>>>(q, kbuf, vtb, aout);
    // x1 = x + (aout@wo^T)*attn_scale  -> q (bf16)
    gemm2<1><<<dim3(8, 32), blk, 0, stream>>>(aout, woc, q, d_in[0], d_in[12], 4096, 1024, 1024, flag, 1, 0);
    ln_kernel<<<4096, 128, 0, stream>>>(q, d_in[8], h, 1024, 1e-5f, flag, 0, 1);
    gemm2<0><<<dim3(32, 32), blk, 0, stream>>>(h, w1c, u, nullptr, nullptr, 4096, 4096, 1024, flag, 0, 0);
    gemm2<3><<<dim3(32, 32), blk, 0, stream>>>(h, w3c, u, u, nullptr, 4096, 4096, 1024, flag, 0, 0);
    gemm2<1><<<dim3(8, 32), blk, 0, stream>>>(u, w2c, d_out, q, d_in[13], 4096, 1024, 4096, flag, 0, 1);
}

// Round 7
// 272.598 us; speedup vs baseline: 1.2411x; 1.0409x over previous
//
#include <hip/hip_runtime.h>

// ---------------------------------------------------------------------------
// CodecTransformerLayer on MI355X (gfx950).  fp32 inputs (sniff-confirmed),
// bf16 internal compute.  Round 7: FFN GEMM rework —
//  * gemm3 (w1/w3): 256x128 tile, wave=64x64 (16 MFMA : 8 ds_read), swapped-
//    operand epilogue with s16x4 stores.
//  * gemm2 (w2): NBUF=5 deep prefetch + bijective XCD swizzle (A-panel L2
//    affinity).  Both: chunk-XOR LDS swizzle (pre-swizzled source + XOR read).
// Attention / LNs unchanged from round 6.
// B=2 S=2048 D=1024 H=16 KVH=8 hd=64 HIDDEN=4096 WINDOW=512
// ---------------------------------------------------------------------------

typedef __bf16 bf16;
typedef __attribute__((ext_vector_type(8))) __bf16 bf16x8;
typedef __attribute__((ext_vector_type(4))) float f32x4;
typedef __attribute__((ext_vector_type(4))) short s16x4;

#define MFMA16(a, b, c) __builtin_amdgcn_mfma_f32_16x16x32_bf16(a, b, c, 0, 0, 0)

__device__ __forceinline__ void gload_lds16(const bf16* g, bf16* l) {
    __builtin_amdgcn_global_load_lds(
        (const __attribute__((address_space(1))) unsigned int*)g,
        (__attribute__((address_space(3))) unsigned int*)l, 16, 0, 0);
}

// ---------------------------------------------------------------------------
__global__ void sniff_kernel(const unsigned short* __restrict__ x, int* __restrict__ flag) {
    __shared__ int s;
    if (threadIdx.x == 0) s = 0;
    __syncthreads();
    int bad = 0;
#pragma unroll
    for (int i = 0; i < 16; ++i) {
        const unsigned short u = x[threadIdx.x * 16 + i];
        const int e = (u >> 7) & 0xFF;
        if (e >= 135) bad = 1;
    }
    if (bad) atomicOr(&s, 1);
    __syncthreads();
    if (threadIdx.x == 0) flag[0] = s;
}

// ---------------------------------------------------------------------------
// Weight gather -> contiguous bf16.  seg map (elements):
// wq[0) wk[1048576) wv[1572864) wo[2097152) w1[3145728) w3[7340032)
// w2[11534336) end 15728640
// ---------------------------------------------------------------------------
__global__ void convert_all_kernel(const void* __restrict__ wq, const void* __restrict__ wk,
                                   const void* __restrict__ wv, const void* __restrict__ wo,
                                   const void* __restrict__ w1, const void* __restrict__ w3,
                                   const void* __restrict__ w2, bf16* __restrict__ dst,
                                   const int* __restrict__ flag) {
    const long e = ((long)blockIdx.x * 256 + threadIdx.x) * 4;
    const void* src; long off;
    if      (e < 1048576)  { src = wq; off = 0; }
    else if (e < 1572864)  { src = wk; off = 1048576; }
    else if (e < 2097152)  { src = wv; off = 1572864; }
    else if (e < 3145728)  { src = wo; off = 2097152; }
    else if (e < 7340032)  { src = w1; off = 3145728; }
    else if (e < 11534336) { src = w3; off = 7340032; }
    else                   { src = w2; off = 11534336; }
    if (flag[0] != 0) {
        const f32x4 v = *(const f32x4*)((const float*)src + (e - off));
        bf16 tmp[4];
#pragma unroll
        for (int j = 0; j < 4; ++j) tmp[j] = (bf16)v[j];
        *(s16x4*)(dst + e) = *(s16x4*)tmp;
    } else {
        *(s16x4*)(dst + e) = *(const s16x4*)((const short*)src + (e - off));
    }
}

// ---------------------------------------------------------------------------
// LayerNorm over last dim W (1024 or 512), one 128-thread block per row.
// ---------------------------------------------------------------------------
__global__ void ln_kernel(const void* __restrict__ in, const void* __restrict__ w,
                          bf16* __restrict__ out, int W, float eps,
                          const int* __restrict__ flag, int in_flv, int w_flv) {
    const int row = blockIdx.x, t = threadIdx.x;
    const int nch = W >> 3;
    const bool act = t < nch;
    const bool f32 = flag[0] != 0;
    float v[8];
    float s = 0.f, s2 = 0.f;
    if (act) {
        if (in_flv && f32) {
            const float* rp = (const float*)in + (size_t)row * W + t * 8;
            const f32x4 a = *(const f32x4*)rp, b = *(const f32x4*)(rp + 4);
#pragma unroll
            for (int j = 0; j < 4; ++j) { v[j] = a[j]; v[4 + j] = b[j]; }
        } else {
            const bf16x8 xv = *(const bf16x8*)((const bf16*)in + (size_t)row * W + t * 8);
#pragma unroll
            for (int j = 0; j < 8; ++j) v[j] = (float)xv[j];
        }
#pragma unroll
        for (int j = 0; j < 8; ++j) { s += v[j]; s2 += v[j] * v[j]; }
    }
#pragma unroll
    for (int off = 32; off; off >>= 1) { s += __shfl_xor(s, off); s2 += __shfl_xor(s2, off); }
    __shared__ float red[4];
    if ((t & 63) == 0) { red[(t >> 6) * 2] = s; red[(t >> 6) * 2 + 1] = s2; }
    __syncthreads();
    const float fs = red[0] + red[2], fs2 = red[1] + red[3];
    const float inw = 1.f / (float)W;
    const float mean = fs * inw;
    const float var = fs2 * inw - mean * mean;
    const float rstd = rsqrtf(var + eps);
    if (act) {
        float wv8[8];
        if (w_flv && f32) {
            const float* wp = (const float*)w + t * 8;
            const f32x4 a = *(const f32x4*)wp, b = *(const f32x4*)(wp + 4);
#pragma unroll
            for (int j = 0; j < 4; ++j) { wv8[j] = a[j]; wv8[4 + j] = b[j]; }
        } else {
            const bf16x8 ww = *(const bf16x8*)((const bf16*)w + t * 8);
#pragma unroll
            for (int j = 0; j < 8; ++j) wv8[j] = (float)ww[j];
        }
        bf16x8 ov;
#pragma unroll
        for (int j = 0; j < 8; ++j) ov[j] = (bf16)((v[j] - mean) * rstd * wv8[j]);
        *(bf16x8*)(out + (size_t)row * W + t * 8) = ov;
    }
}

// ---------------------------------------------------------------------------
// Pipelined GEMM  C[M,N] = A[M,K] * B[N,K]^T.  128x128 tile, BK=32, 8 waves
// (2Mx4N), NBUF-deep counted-vmcnt pipeline (steady vmcnt = 2*(NBUF-2)),
// chunk-XOR LDS swizzle.  SWZ=1: bijective XCD block remap (needs gy%8==0).
// Epilogues: 0 plain; 1 res+acc*scale[col]; 3 silu(res)*acc;
//            4 fused QKV split (q | k | v-transposed).
// ---------------------------------------------------------------------------
template <int EPI, int NBUF, int SWZ>
__global__ __launch_bounds__(512, 4)
void gemm2(const bf16* __restrict__ A, const bf16* __restrict__ B,
           void* __restrict__ Cout, const void* __restrict__ res,
           const void* __restrict__ scale, int M, int N, int K,
           const int* __restrict__ flag, int res_flv, int out_flv) {
    __shared__ bf16 LDS[NBUF * 8192];
    const bool f32 = flag[0] != 0;
    const int t = threadIdx.x;
    const int wv = t >> 6, ln = t & 63;
    const int qr = ln & 15, g = ln >> 4;
    const int wr = wv >> 2, wc = wv & 3;
    int bx = blockIdx.x, by = blockIdx.y;
    if (SWZ) {
        const int bid = by * gridDim.x + bx;
        const int g8 = bid & 7, m = bid >> 3;
        bx = m % gridDim.x;
        by = g8 + 8 * (m / gridDim.x);
    }
    const int row0 = by * 128, col0 = bx * 128;

    f32x4 acc[4][2] = {};

    // chunk-XOR swizzle: global source chunk (t&3)^((t>>2)&3) -> linear LDS
    const int cx = ((t & 3) ^ ((t >> 2) & 3)) * 8;
    const bf16* aSrc = A + (size_t)(row0 + (t >> 2)) * K + cx;
    const bf16* bSrc = B + (size_t)(col0 + (t >> 2)) * K + cx;
    const int gx8 = (g ^ (qr & 3)) * 8;              // swizzled read chunk
    const int NIT = K >> 5;

#define STAGE(bi, k0)                                              \
    do {                                                           \
        bf16* lb = LDS + (bi) * 8192 + wv * 512;                   \
        gload_lds16(aSrc + (k0), lb);                              \
        gload_lds16(bSrc + (k0), lb + 4096);                       \
    } while (0)

#pragma unroll
    for (int pb = 0; pb < NBUF - 1; ++pb) STAGE(pb, pb * 32);
    if constexpr (NBUF == 3) asm volatile("s_waitcnt vmcnt(2)" ::: "memory");
    else                     asm volatile("s_waitcnt vmcnt(6)" ::: "memory");
    __builtin_amdgcn_s_barrier();
    __builtin_amdgcn_sched_barrier(0);

    int cur = 0, sb = NBUF - 1;
    for (int it = 0; it < NIT; ++it) {
        const bool more = (it + NBUF - 1) < NIT;
        if (more) STAGE(sb, (it + NBUF - 1) * 32);
        const bf16* bufA = LDS + cur * 8192;
        const bf16* bufB = bufA + 4096;
        bf16x8 af[4], bfr[2];
#pragma unroll
        for (int i = 0; i < 4; ++i)
            af[i] = *(const bf16x8*)&bufA[(wr * 64 + i * 16 + qr) * 32 + gx8];
#pragma unroll
        for (int j = 0; j < 2; ++j)
            bfr[j] = *(const bf16x8*)&bufB[(wc * 32 + j * 16 + qr) * 32 + gx8];
#pragma unroll
        for (int i = 0; i < 4; ++i)
#pragma unroll
            for (int j = 0; j < 2; ++j)
                acc[i][j] = MFMA16(af[i], bfr[j], acc[i][j]);
        if (more) {
            if constexpr (NBUF == 3) asm volatile("s_waitcnt vmcnt(2)" ::: "memory");
            else                     asm volatile("s_waitcnt vmcnt(6)" ::: "memory");
        } else {
            asm volatile("s_waitcnt vmcnt(0)" ::: "memory");
        }
        __builtin_amdgcn_s_barrier();
        __builtin_amdgcn_sched_barrier(0);
        cur = cur + 1 == NBUF ? 0 : cur + 1;
        sb  = sb + 1 == NBUF ? 0 : sb + 1;
    }
#undef STAGE

#pragma unroll
    for (int i = 0; i < 4; ++i) {
#pragma unroll
        for (int j = 0; j < 2; ++j) {
            const int rr0 = row0 + wr * 64 + i * 16 + g * 4;  // C/D row=(l>>4)*4+r
            const int cc  = col0 + wc * 32 + j * 16 + qr;     //     col=l&15
            if (EPI == 4) {
                if (cc < 1024) {                 // q
#pragma unroll
                    for (int r = 0; r < 4; ++r)
                        ((bf16*)Cout)[(size_t)(rr0 + r) * 1024 + cc] = (bf16)acc[i][j][r];
                } else if (cc < 1536) {          // k
#pragma unroll
                    for (int r = 0; r < 4; ++r)
                        ((bf16*)res)[(size_t)(rr0 + r) * 512 + (cc - 1024)] = (bf16)acc[i][j][r];
                } else {                         // v transposed bf16: Vt[b][kvh][d][s]
                    const int kv = cc - 1536, kvh = kv >> 6, d = kv & 63;
                    const int bb = rr0 >> 11, s0 = rr0 & 2047;
                    bf16 tmp[4];
#pragma unroll
                    for (int r = 0; r < 4; ++r) tmp[r] = (bf16)acc[i][j][r];
                    *(s16x4*)((bf16*)scale + (((size_t)bb * 8 + kvh) * 64 + d) * 2048 + s0) = *(s16x4*)tmp;
                }
            } else {
                float scv = 0.f;
                if (EPI == 1)
                    scv = f32 ? ((const float*)scale)[cc] : (float)((const bf16*)scale)[cc];
#pragma unroll
                for (int r = 0; r < 4; ++r) {
                    const size_t idx = (size_t)(rr0 + r) * N + cc;
                    float vv = acc[i][j][r];
                    if (EPI == 1) {
                        const float rv = (res_flv && f32) ? ((const float*)res)[idx]
                                                          : (float)((const bf16*)res)[idx];
                        vv = rv + vv * scv;
                    }
                    if (EPI == 3) {
                        const float uv = (float)((const bf16*)res)[idx];
                        vv = uv / (1.f + __expf(-uv)) * vv;
                    }
                    if (out_flv && f32) ((float*)Cout)[idx] = vv;
                    else                ((bf16*)Cout)[idx] = (bf16)vv;
                }
            }
        }
    }
}

// ---------------------------------------------------------------------------
// gemm3: C[M,N] = A[M,K]*B[N,K]^T, 256x128 tile, BK=32, 8 waves (4Mx2N, wave
// tile 64x64 -> 16 MFMA : 8 ds_read), 3-buffer vmcnt(3) pipeline (3 loads/
// tile), chunk-XOR LDS swizzle.  Swapped-operand MFMA: lane holds 4
// CONSECUTIVE C columns -> s16x4 stores.  EPI 0: C=acc; EPI 3: C=silu(res)*acc.
// ---------------------------------------------------------------------------
template <int EPI>
__global__ __launch_bounds__(512, 4)
void gemm3(const bf16* __restrict__ A, const bf16* __restrict__ B,
           bf16* __restrict__ C, const bf16* __restrict__ res,
           int M, int N, int K) {
    __shared__ bf16 LDS[3 * 12288];      // per buf: A 16KB | B 8KB
    const int t = threadIdx.x;
    const int wv = t >> 6, ln = t & 63;
    const int qr = ln & 15, g = ln >> 4;
    const int wr = wv >> 1, wc = wv & 1;
    const int row0 = blockIdx.y * 256, col0 = blockIdx.x * 128;

    f32x4 acc[4][4] = {};

    const int cx = ((t & 3) ^ ((t >> 2) & 3)) * 8;
    const bf16* aSrc  = A + (size_t)(row0 + (t >> 2)) * K + cx;
    const bf16* aSrc2 = A + (size_t)(row0 + 128 + (t >> 2)) * K + cx;
    const bf16* bSrc  = B + (size_t)(col0 + (t >> 2)) * K + cx;
    const int gx8 = (g ^ (qr & 3)) * 8;
    const int NIT = K >> 5;

#define STAGE3(bi, k0)                                             \
    do {                                                           \
        bf16* lb = LDS + (bi) * 12288 + wv * 512;                  \
        gload_lds16(aSrc + (k0), lb);                              \
        gload_lds16(aSrc2 + (k0), lb + 4096);                      \
        gload_lds16(bSrc + (k0), lb + 8192);                       \
    } while (0)

    STAGE3(0, 0);
    STAGE3(1, 32);
    asm volatile("s_waitcnt vmcnt(3)" ::: "memory");
    __builtin_amdgcn_s_barrier();
    __builtin_amdgcn_sched_barrier(0);

    int cur = 0, sb = 2;
    for (int it = 0; it < NIT; ++it) {
        const bool more = (it + 2) < NIT;
        if (more) STAGE3(sb, (it + 2) * 32);
        const bf16* bufA = LDS + cur * 12288;
        const bf16* bufB = bufA + 8192;
        bf16x8 af[4], bfr[4];
#pragma unroll
        for (int i = 0; i < 4; ++i)
            af[i] = *(const bf16x8*)&bufA[(wr * 64 + i * 16 + qr) * 32 + gx8];
#pragma unroll
        for (int j = 0; j < 4; ++j)
            bfr[j] = *(const bf16x8*)&bufB[(wc * 64 + j * 16 + qr) * 32 + gx8];
#pragma unroll
        for (int i = 0; i < 4; ++i)
#pragma unroll
            for (int j = 0; j < 4; ++j)
                acc[i][j] = MFMA16(bfr[j], af[i], acc[i][j]);   // swapped!
        if (more) asm volatile("s_waitcnt vmcnt(3)" ::: "memory");
        else      asm volatile("s_waitcnt vmcnt(0)" ::: "memory");
        __builtin_amdgcn_s_barrier();
        __builtin_amdgcn_sched_barrier(0);
        cur = cur == 2 ? 0 : cur + 1;
        sb  = sb  == 2 ? 0 : sb  + 1;
    }
#undef STAGE3

    // swapped C/D layout: C row = row0+wr*64+i*16+qr, C cols = col0+wc*64+j*16+g*4+r
#pragma unroll
    for (int i = 0; i < 4; ++i) {
        const int row = row0 + wr * 64 + i * 16 + qr;
#pragma unroll
        for (int j = 0; j < 4; ++j) {
            const int col = col0 + wc * 64 + j * 16 + g * 4;
            const size_t idx = (size_t)row * N + col;
            bf16 tmp[4];
            if (EPI == 3) {
                const s16x4 rv4 = *(const s16x4*)(res + idx);
#pragma unroll
                for (int r = 0; r < 4; ++r) {
                    bf16 ub; *(short*)&ub = rv4[r];
                    const float uv = (float)ub;
                    tmp[r] = (bf16)(uv / (1.f + __expf(-uv)) * acc[i][j][r]);
                }
            } else {
#pragma unroll
                for (int r = 0; r < 4; ++r) tmp[r] = (bf16)acc[i][j][r];
            }
            *(s16x4*)(C + idx) = *(s16x4*)tmp;
        }
    }
}

// ---------------------------------------------------------------------------
// Windowed-ALiBi GQA flash attention (unchanged from round 6).
// ---------------------------------------------------------------------------
__global__ __launch_bounds__(256)
void attn_kernel(const bf16* __restrict__ qn, const bf16* __restrict__ kn,
                 const bf16* __restrict__ vt, bf16* __restrict__ aout) {
    __shared__ bf16 SH[3 * 4096];      // buf: K [32 key][64 hd] | V [64 d][32 key]
    const int t = threadIdx.x, wv = t >> 6, ln = t & 63;
    const int qr = ln & 15, g = ln >> 4;
    const int h = blockIdx.y, b = blockIdx.z, kvh = h >> 1;
    const int q0blk = blockIdx.x * 64;
    const int qa = q0blk + wv * 16 + qr;
    const float slope = exp2f(-0.5f * (float)(h + 1));

    const bf16* qrow = qn + ((size_t)(b * 2048 + qa)) * 1024 + h * 64;
    const bf16x8 qb0 = *(const bf16x8*)(qrow + g * 8);
    const bf16x8 qb1 = *(const bf16x8*)(qrow + 32 + g * 8);

    const bf16* kbase = kn + (size_t)b * 2048 * 512 + kvh * 64;
    const bf16* vbase = vt + ((size_t)(b * 8 + kvh) * 64) * 2048;
    const int krow_l = t >> 3;
    const int kcsrc  = (t & 7) ^ ((t >> 3) & 7);
    const int vd     = t >> 2;
    const int vcsrc  = (t & 3) ^ ((t >> 2) & 3);
    const bf16* kgsrc = kbase + kcsrc * 8;
    const bf16* vgsrc = vbase + (size_t)vd * 2048;
    bf16* lK0 = SH + wv * 512;
    bf16* lV0 = SH + 2048 + wv * 512;

#define STAGE_T(kts, bi)                                           \
    do {                                                           \
        int ksrc = (kts) + krow_l;                                 \
        ksrc = ksrc > 2047 ? 2047 : ksrc;                          \
        gload_lds16(kgsrc + (size_t)ksrc * 512, lK0 + (bi) * 4096);\
        int vsrc = (kts) + vcsrc * 8;                              \
        vsrc = vsrc > 2040 ? 2040 : vsrc;                          \
        gload_lds16(vgsrc + vsrc, lV0 + (bi) * 4096);              \
    } while (0)

    STAGE_T(q0blk, 0);
    STAGE_T(q0blk + 32, 1);
    STAGE_T(q0blk + 64, 2);
    asm volatile("s_waitcnt vmcnt(4)" ::: "memory");
    __builtin_amdgcn_s_barrier();
    __builtin_amdgcn_sched_barrier(0);

    f32x4 o[4] = {};
    float mrun = -1e29f, lsum = 0.f;
    int cur = 0;

    for (int it = 0; it < 18; ++it) {
        const int kt = q0blk + it * 32;
        const bf16* Kb = SH + cur * 4096;
        const bf16* Vb = Kb + 2048;

        f32x4 sc[2] = {f32x4{0, 0, 0, 0}, f32x4{0, 0, 0, 0}};
#pragma unroll
        for (int ks = 0; ks < 2; ++ks) {
            const int lrow = ks * 16 + qr;
            const int sw = (lrow & 7) * 8;
            sc[ks] = MFMA16(*(const bf16x8*)&Kb[lrow * 64 + (((g) * 8) ^ sw)],        qb0, sc[ks]);
            sc[ks] = MFMA16(*(const bf16x8*)&Kb[lrow * 64 + (((4 + g) * 8) ^ sw)],    qb1, sc[ks]);
        }
        float s[2][4], p[2][4];
        float tmax = -1e30f;
#pragma unroll
        for (int ks = 0; ks < 2; ++ks)
#pragma unroll
            for (int r = 0; r < 4; ++r) {
                const int key = kt + ks * 16 + g * 4 + r;
                const int dist = key - qa;
                const bool valid = (dist >= 0) && (dist <= 512) && (key < 2048);
                const float sv = valid ? sc[ks][r] * 0.125f - slope * (float)dist : -1e30f;
                s[ks][r] = sv;
                tmax = fmaxf(tmax, sv);
            }
        tmax = fmaxf(tmax, __shfl_xor(tmax, 16));
        tmax = fmaxf(tmax, __shfl_xor(tmax, 32));
        const float mnew = fmaxf(mrun, tmax);
        const float alpha = __expf(mrun - mnew);
        mrun = mnew;
        float ps = 0.f;
#pragma unroll
        for (int ks = 0; ks < 2; ++ks)
#pragma unroll
            for (int r = 0; r < 4; ++r) { p[ks][r] = __expf(s[ks][r] - mnew); ps += p[ks][r]; }
        lsum = lsum * alpha + ps;
#pragma unroll
        for (int fd = 0; fd < 4; ++fd) o[fd] *= alpha;

        bf16x8 pb;
#pragma unroll
        for (int j = 0; j < 8; ++j) {
            const int srcl = (((2 * g + (j >> 2)) & 3) << 4) | qr;
            const float v0 = __shfl(p[0][j & 3], srcl);
            const float v1 = __shfl(p[1][j & 3], srcl);
            pb[j] = (bf16)((g & 2) ? v1 : v0);
        }
#pragma unroll
        for (int fd = 0; fd < 4; ++fd) {
            const int d = fd * 16 + qr;
            const bf16x8 va = *(const bf16x8*)&Vb[d * 32 + ((g ^ (d & 3)) * 8)];
            o[fd] = MFMA16(va, pb, o[fd]);
        }

        __builtin_amdgcn_s_barrier();
        if (it + 3 < 18) {
            STAGE_T(kt + 96, cur);
            asm volatile("s_waitcnt vmcnt(4)" ::: "memory");
        } else {
            asm volatile("s_waitcnt vmcnt(0)" ::: "memory");
        }
        __builtin_amdgcn_s_barrier();
        __builtin_amdgcn_sched_barrier(0);
        cur = cur == 2 ? 0 : cur + 1;
    }
#undef STAGE_T

    float lt = lsum + __shfl_xor(lsum, 16);
    lt += __shfl_xor(lt, 32);
    lt = fmaxf(lt, 1e-30f);
    const float inv = 1.f / lt;
    bf16* orow = aout + ((size_t)(b * 2048 + qa)) * 1024 + h * 64;
#pragma unroll
    for (int fd = 0; fd < 4; ++fd) {
        bf16 tmp[4];
#pragma unroll
        for (int r = 0; r < 4; ++r) tmp[r] = (bf16)(o[fd][r] * inv);
        *(s16x4*)(orow + fd * 16 + g * 4) = *(s16x4*)tmp;
    }
}

// ---------------------------------------------------------------------------
extern "C" void kernel_launch(void* const* d_in, const int* in_sizes, int n_in,
                              void* d_out, int out_size, void* d_ws, size_t ws_size,
                              hipStream_t stream) {
    int* flag = (int*)d_ws;
    bf16* base = (bf16*)d_ws + 64;
    bf16* h    = base;                // 4096*1024  (reused as h2)
    bf16* q    = h + 4194304;         // 4096*1024  (reused as x1 after attn)
    bf16* kbuf = q + 4194304;         // 4096*512
    bf16* vtb  = kbuf + 2097152;      // 2*8*64*2048
    bf16* aout = vtb + 2097152;       // 4096*1024
    bf16* u    = aout + 4194304;      // 4096*4096  (reused as act)
    bf16* wcv  = u + 16777216;        // 15728640 converted weights (contiguous)

    bf16* woc = wcv + 2097152;
    bf16* w1c = wcv + 3145728;
    bf16* w3c = wcv + 7340032;
    bf16* w2c = wcv + 11534336;

    const dim3 blk(512);
    sniff_kernel<<<1, 256, 0, stream>>>((const unsigned short*)d_in[0], flag);
    convert_all_kernel<<<15360, 256, 0, stream>>>(
        d_in[1], d_in[2], d_in[3], d_in[4], d_in[9], d_in[11], d_in[10], wcv, flag);

    ln_kernel<<<4096, 128, 0, stream>>>(d_in[0], d_in[7], h, 1024, 1e-5f, flag, 1, 1);
    // fused QKV: B = [wq;wk;wv] rows, N=2048.  EPI4: Cout=q, res=kbuf, scale=vtb
    gemm2<4, 3, 0><<<dim3(16, 32), blk, 0, stream>>>(h, wcv, q, kbuf, vtb, 4096, 2048, 1024, flag, 0, 0);
    ln_kernel<<<4096, 128, 0, stream>>>(q, d_in[5], q, 1024, 1e-6f, flag, 0, 1);
    ln_kernel<<<4096, 128, 0, stream>>>(kbuf, d_in[6], kbuf, 512, 1e-6f, flag, 0, 1);
    attn_kernel<<<dim3(32, 16, 2), dim3(256), 0, stream>>>(q, kbuf, vtb, aout);
    // x1 = x + (aout@wo^T)*attn_scale  -> q (bf16)
    gemm2<1, 3, 1><<<dim3(8, 32), blk, 0, stream>>>(aout, woc, q, d_in[0], d_in[12], 4096, 1024, 1024, flag, 1, 0);
    ln_kernel<<<4096, 128, 0, stream>>>(q, d_in[8], h, 1024, 1e-5f, flag, 0, 1);
    gemm3<0><<<dim3(32, 16), blk, 0, stream>>>(h, w1c, u, nullptr, 4096, 4096, 1024);
    gemm3<3><<<dim3(32, 16), blk, 0, stream>>>(h, w3c, u, u,       4096, 4096, 1024);
    gemm2<1, 5, 1><<<dim3(8, 32), blk, 0, stream>>>(u, w2c, d_out, q, d_in[13], 4096, 1024, 4096, flag, 0, 1);
}

// Round 8
// 267.118 us; speedup vs baseline: 1.2666x; 1.0205x over previous
//
#include <hip/hip_runtime.h>

// ---------------------------------------------------------------------------
// CodecTransformerLayer on MI355X (gfx950).  fp32 inputs (sniff-confirmed),
// bf16 internal compute.  Round 8:
//  * w2 GEMM split-K=2 (512 blocks = 2/CU -> fills barrier-lockstep gaps),
//    bf16 partials + fused reduce kernel (out = x1 + (p0+p1)*scale).
//  * attention: single-barrier 3-buffer pipeline (exact gemm2 ledger).
// B=2 S=2048 D=1024 H=16 KVH=8 hd=64 HIDDEN=4096 WINDOW=512
// ---------------------------------------------------------------------------

typedef __bf16 bf16;
typedef __attribute__((ext_vector_type(8))) __bf16 bf16x8;
typedef __attribute__((ext_vector_type(4))) float f32x4;
typedef __attribute__((ext_vector_type(4))) short s16x4;

#define MFMA16(a, b, c) __builtin_amdgcn_mfma_f32_16x16x32_bf16(a, b, c, 0, 0, 0)

__device__ __forceinline__ void gload_lds16(const bf16* g, bf16* l) {
    __builtin_amdgcn_global_load_lds(
        (const __attribute__((address_space(1))) unsigned int*)g,
        (__attribute__((address_space(3))) unsigned int*)l, 16, 0, 0);
}

// ---------------------------------------------------------------------------
__global__ void sniff_kernel(const unsigned short* __restrict__ x, int* __restrict__ flag) {
    __shared__ int s;
    if (threadIdx.x == 0) s = 0;
    __syncthreads();
    int bad = 0;
#pragma unroll
    for (int i = 0; i < 16; ++i) {
        const unsigned short u = x[threadIdx.x * 16 + i];
        const int e = (u >> 7) & 0xFF;
        if (e >= 135) bad = 1;
    }
    if (bad) atomicOr(&s, 1);
    __syncthreads();
    if (threadIdx.x == 0) flag[0] = s;
}

// ---------------------------------------------------------------------------
// Weight gather -> contiguous bf16.  seg map (elements):
// wq[0) wk[1048576) wv[1572864) wo[2097152) w1[3145728) w3[7340032)
// w2[11534336) end 15728640
// ---------------------------------------------------------------------------
__global__ void convert_all_kernel(const void* __restrict__ wq, const void* __restrict__ wk,
                                   const void* __restrict__ wv, const void* __restrict__ wo,
                                   const void* __restrict__ w1, const void* __restrict__ w3,
                                   const void* __restrict__ w2, bf16* __restrict__ dst,
                                   const int* __restrict__ flag) {
    const long e = ((long)blockIdx.x * 256 + threadIdx.x) * 4;
    const void* src; long off;
    if      (e < 1048576)  { src = wq; off = 0; }
    else if (e < 1572864)  { src = wk; off = 1048576; }
    else if (e < 2097152)  { src = wv; off = 1572864; }
    else if (e < 3145728)  { src = wo; off = 2097152; }
    else if (e < 7340032)  { src = w1; off = 3145728; }
    else if (e < 11534336) { src = w3; off = 7340032; }
    else                   { src = w2; off = 11534336; }
    if (flag[0] != 0) {
        const f32x4 v = *(const f32x4*)((const float*)src + (e - off));
        bf16 tmp[4];
#pragma unroll
        for (int j = 0; j < 4; ++j) tmp[j] = (bf16)v[j];
        *(s16x4*)(dst + e) = *(s16x4*)tmp;
    } else {
        *(s16x4*)(dst + e) = *(const s16x4*)((const short*)src + (e - off));
    }
}

// ---------------------------------------------------------------------------
// LayerNorm over last dim W (1024 or 512), one 128-thread block per row.
// ---------------------------------------------------------------------------
__global__ void ln_kernel(const void* __restrict__ in, const void* __restrict__ w,
                          bf16* __restrict__ out, int W, float eps,
                          const int* __restrict__ flag, int in_flv, int w_flv) {
    const int row = blockIdx.x, t = threadIdx.x;
    const int nch = W >> 3;
    const bool act = t < nch;
    const bool f32 = flag[0] != 0;
    float v[8];
    float s = 0.f, s2 = 0.f;
    if (act) {
        if (in_flv && f32) {
            const float* rp = (const float*)in + (size_t)row * W + t * 8;
            const f32x4 a = *(const f32x4*)rp, b = *(const f32x4*)(rp + 4);
#pragma unroll
            for (int j = 0; j < 4; ++j) { v[j] = a[j]; v[4 + j] = b[j]; }
        } else {
            const bf16x8 xv = *(const bf16x8*)((const bf16*)in + (size_t)row * W + t * 8);
#pragma unroll
            for (int j = 0; j < 8; ++j) v[j] = (float)xv[j];
        }
#pragma unroll
        for (int j = 0; j < 8; ++j) { s += v[j]; s2 += v[j] * v[j]; }
    }
#pragma unroll
    for (int off = 32; off; off >>= 1) { s += __shfl_xor(s, off); s2 += __shfl_xor(s2, off); }
    __shared__ float red[4];
    if ((t & 63) == 0) { red[(t >> 6) * 2] = s; red[(t >> 6) * 2 + 1] = s2; }
    __syncthreads();
    const float fs = red[0] + red[2], fs2 = red[1] + red[3];
    const float inw = 1.f / (float)W;
    const float mean = fs * inw;
    const float var = fs2 * inw - mean * mean;
    const float rstd = rsqrtf(var + eps);
    if (act) {
        float wv8[8];
        if (w_flv && f32) {
            const float* wp = (const float*)w + t * 8;
            const f32x4 a = *(const f32x4*)wp, b = *(const f32x4*)(wp + 4);
#pragma unroll
            for (int j = 0; j < 4; ++j) { wv8[j] = a[j]; wv8[4 + j] = b[j]; }
        } else {
            const bf16x8 ww = *(const bf16x8*)((const bf16*)w + t * 8);
#pragma unroll
            for (int j = 0; j < 8; ++j) wv8[j] = (float)ww[j];
        }
        bf16x8 ov;
#pragma unroll
        for (int j = 0; j < 8; ++j) ov[j] = (bf16)((v[j] - mean) * rstd * wv8[j]);
        *(bf16x8*)(out + (size_t)row * W + t * 8) = ov;
    }
}

// ---------------------------------------------------------------------------
// Split-K reduce: out = x1 + (p0+p1)*scale[col].  p bf16 [2][4096][1024].
// ---------------------------------------------------------------------------
__global__ void reduce_k(const bf16* __restrict__ p, const bf16* __restrict__ x1,
                         const void* __restrict__ scale, void* __restrict__ out,
                         const int* __restrict__ flag) {
    const bool f32 = flag[0] != 0;
    const size_t i8 = ((size_t)blockIdx.x * 256 + threadIdx.x) * 8;
    const int col = (int)(i8 & 1023);
    const bf16x8 a = *(const bf16x8*)(p + i8);
    const bf16x8 b = *(const bf16x8*)(p + 4194304 + i8);
    const bf16x8 r = *(const bf16x8*)(x1 + i8);
    float sc8[8];
    if (f32) {
        const f32x4 s0 = *(const f32x4*)((const float*)scale + col);
        const f32x4 s1 = *(const f32x4*)((const float*)scale + col + 4);
#pragma unroll
        for (int j = 0; j < 4; ++j) { sc8[j] = s0[j]; sc8[4 + j] = s1[j]; }
    } else {
        const bf16x8 sb = *(const bf16x8*)((const bf16*)scale + col);
#pragma unroll
        for (int j = 0; j < 8; ++j) sc8[j] = (float)sb[j];
    }
    float o[8];
#pragma unroll
    for (int j = 0; j < 8; ++j)
        o[j] = (float)r[j] + ((float)a[j] + (float)b[j]) * sc8[j];
    if (f32) {
        f32x4 o0, o1;
#pragma unroll
        for (int j = 0; j < 4; ++j) { o0[j] = o[j]; o1[j] = o[4 + j]; }
        *(f32x4*)((float*)out + i8) = o0;
        *(f32x4*)((float*)out + i8 + 4) = o1;
    } else {
        bf16x8 ov;
#pragma unroll
        for (int j = 0; j < 8; ++j) ov[j] = (bf16)o[j];
        *(bf16x8*)((bf16*)out + i8) = ov;
    }
}

// ---------------------------------------------------------------------------
// Pipelined GEMM  C[M,N] = A[M,K] * B[N,K]^T.  128x128 tile, BK=32, 8 waves
// (2Mx4N), NBUF-deep counted-vmcnt pipeline, chunk-XOR LDS swizzle.
// SWZ=1: bijective XCD block remap.  SPLITK=1: blockIdx.z selects K half,
// output -> partial region z (plain bf16, EPI must be 0).
// Epilogues: 0 plain; 1 res+acc*scale[col]; 3 silu(res)*acc; 4 QKV split.
// ---------------------------------------------------------------------------
template <int EPI, int NBUF, int SWZ, int SPLITK>
__global__ __launch_bounds__(512, 4)
void gemm2(const bf16* __restrict__ A, const bf16* __restrict__ B,
           void* __restrict__ Cout, const void* __restrict__ res,
           const void* __restrict__ scale, int M, int N, int K,
           const int* __restrict__ flag, int res_flv, int out_flv) {
    __shared__ bf16 LDS[NBUF * 8192];
    const bool f32 = flag[0] != 0;
    const int t = threadIdx.x;
    const int wv = t >> 6, ln = t & 63;
    const int qr = ln & 15, g = ln >> 4;
    const int wr = wv >> 2, wc = wv & 3;
    int bx = blockIdx.x, by = blockIdx.y;
    if (SWZ) {
        const int bid = by * gridDim.x + bx;
        const int g8 = bid & 7, m = bid >> 3;
        bx = m % gridDim.x;
        by = g8 + 8 * (m / gridDim.x);
    }
    const int row0 = by * 128, col0 = bx * 128;

    const int Koff = SPLITK ? (int)blockIdx.z * (K >> 1) : 0;
    const int Keff = SPLITK ? (K >> 1) : K;
    if (SPLITK) Cout = (void*)((bf16*)Cout + (size_t)blockIdx.z * ((size_t)M * N));

    f32x4 acc[4][2] = {};

    const int cx = ((t & 3) ^ ((t >> 2) & 3)) * 8;
    const bf16* aSrc = A + (size_t)(row0 + (t >> 2)) * K + Koff + cx;
    const bf16* bSrc = B + (size_t)(col0 + (t >> 2)) * K + Koff + cx;
    const int gx8 = (g ^ (qr & 3)) * 8;              // swizzled read chunk
    const int NIT = Keff >> 5;

#define STAGE(bi, k0)                                              \
    do {                                                           \
        bf16* lb = LDS + (bi) * 8192 + wv * 512;                   \
        gload_lds16(aSrc + (k0), lb);                              \
        gload_lds16(bSrc + (k0), lb + 4096);                       \
    } while (0)

#pragma unroll
    for (int pb = 0; pb < NBUF - 1; ++pb) STAGE(pb, pb * 32);
    if constexpr (NBUF == 3) asm volatile("s_waitcnt vmcnt(2)" ::: "memory");
    else                     asm volatile("s_waitcnt vmcnt(6)" ::: "memory");
    __builtin_amdgcn_s_barrier();
    __builtin_amdgcn_sched_barrier(0);

    int cur = 0, sb = NBUF - 1;
    for (int it = 0; it < NIT; ++it) {
        const bool more = (it + NBUF - 1) < NIT;
        if (more) STAGE(sb, (it + NBUF - 1) * 32);
        const bf16* bufA = LDS + cur * 8192;
        const bf16* bufB = bufA + 4096;
        bf16x8 af[4], bfr[2];
#pragma unroll
        for (int i = 0; i < 4; ++i)
            af[i] = *(const bf16x8*)&bufA[(wr * 64 + i * 16 + qr) * 32 + gx8];
#pragma unroll
        for (int j = 0; j < 2; ++j)
            bfr[j] = *(const bf16x8*)&bufB[(wc * 32 + j * 16 + qr) * 32 + gx8];
#pragma unroll
        for (int i = 0; i < 4; ++i)
#pragma unroll
            for (int j = 0; j < 2; ++j)
                acc[i][j] = MFMA16(af[i], bfr[j], acc[i][j]);
        if (more) {
            if constexpr (NBUF == 3) asm volatile("s_waitcnt vmcnt(2)" ::: "memory");
            else                     asm volatile("s_waitcnt vmcnt(6)" ::: "memory");
        } else {
            asm volatile("s_waitcnt vmcnt(0)" ::: "memory");
        }
        __builtin_amdgcn_s_barrier();
        __builtin_amdgcn_sched_barrier(0);
        cur = cur + 1 == NBUF ? 0 : cur + 1;
        sb  = sb + 1 == NBUF ? 0 : sb + 1;
    }
#undef STAGE

#pragma unroll
    for (int i = 0; i < 4; ++i) {
#pragma unroll
        for (int j = 0; j < 2; ++j) {
            const int rr0 = row0 + wr * 64 + i * 16 + g * 4;  // C/D row=(l>>4)*4+r
            const int cc  = col0 + wc * 32 + j * 16 + qr;     //     col=l&15
            if (EPI == 4) {
                if (cc < 1024) {                 // q
#pragma unroll
                    for (int r = 0; r < 4; ++r)
                        ((bf16*)Cout)[(size_t)(rr0 + r) * 1024 + cc] = (bf16)acc[i][j][r];
                } else if (cc < 1536) {          // k
#pragma unroll
                    for (int r = 0; r < 4; ++r)
                        ((bf16*)res)[(size_t)(rr0 + r) * 512 + (cc - 1024)] = (bf16)acc[i][j][r];
                } else {                         // v transposed bf16: Vt[b][kvh][d][s]
                    const int kv = cc - 1536, kvh = kv >> 6, d = kv & 63;
                    const int bb = rr0 >> 11, s0 = rr0 & 2047;
                    bf16 tmp[4];
#pragma unroll
                    for (int r = 0; r < 4; ++r) tmp[r] = (bf16)acc[i][j][r];
                    *(s16x4*)((bf16*)scale + (((size_t)bb * 8 + kvh) * 64 + d) * 2048 + s0) = *(s16x4*)tmp;
                }
            } else {
                float scv = 0.f;
                if (EPI == 1)
                    scv = f32 ? ((const float*)scale)[cc] : (float)((const bf16*)scale)[cc];
#pragma unroll
                for (int r = 0; r < 4; ++r) {
                    const size_t idx = (size_t)(rr0 + r) * N + cc;
                    float vv = acc[i][j][r];
                    if (EPI == 1) {
                        const float rv = (res_flv && f32) ? ((const float*)res)[idx]
                                                          : (float)((const bf16*)res)[idx];
                        vv = rv + vv * scv;
                    }
                    if (EPI == 3) {
                        const float uv = (float)((const bf16*)res)[idx];
                        vv = uv / (1.f + __expf(-uv)) * vv;
                    }
                    if (out_flv && f32) ((float*)Cout)[idx] = vv;
                    else                ((bf16*)Cout)[idx] = (bf16)vv;
                }
            }
        }
    }
}

// ---------------------------------------------------------------------------
// gemm3: 256x128 tile, BK=32, 8 waves (4Mx2N, wave 64x64), 3-buffer vmcnt(3)
// pipeline, chunk-XOR swizzle, swapped-operand MFMA -> s16x4 stores.
// (unchanged from round 7)
// ---------------------------------------------------------------------------
template <int EPI>
__global__ __launch_bounds__(512, 4)
void gemm3(const bf16* __restrict__ A, const bf16* __restrict__ B,
           bf16* __restrict__ C, const bf16* __restrict__ res,
           int M, int N, int K) {
    __shared__ bf16 LDS[3 * 12288];      // per buf: A 16KB | B 8KB
    const int t = threadIdx.x;
    const int wv = t >> 6, ln = t & 63;
    const int qr = ln & 15, g = ln >> 4;
    const int wr = wv >> 1, wc = wv & 1;
    const int row0 = blockIdx.y * 256, col0 = blockIdx.x * 128;

    f32x4 acc[4][4] = {};

    const int cx = ((t & 3) ^ ((t >> 2) & 3)) * 8;
    const bf16* aSrc  = A + (size_t)(row0 + (t >> 2)) * K + cx;
    const bf16* aSrc2 = A + (size_t)(row0 + 128 + (t >> 2)) * K + cx;
    const bf16* bSrc  = B + (size_t)(col0 + (t >> 2)) * K + cx;
    const int gx8 = (g ^ (qr & 3)) * 8;
    const int NIT = K >> 5;

#define STAGE3(bi, k0)                                             \
    do {                                                           \
        bf16* lb = LDS + (bi) * 12288 + wv * 512;                  \
        gload_lds16(aSrc + (k0), lb);                              \
        gload_lds16(aSrc2 + (k0), lb + 4096);                      \
        gload_lds16(bSrc + (k0), lb + 8192);                       \
    } while (0)

    STAGE3(0, 0);
    STAGE3(1, 32);
    asm volatile("s_waitcnt vmcnt(3)" ::: "memory");
    __builtin_amdgcn_s_barrier();
    __builtin_amdgcn_sched_barrier(0);

    int cur = 0, sb = 2;
    for (int it = 0; it < NIT; ++it) {
        const bool more = (it + 2) < NIT;
        if (more) STAGE3(sb, (it + 2) * 32);
        const bf16* bufA = LDS + cur * 12288;
        const bf16* bufB = bufA + 8192;
        bf16x8 af[4], bfr[4];
#pragma unroll
        for (int i = 0; i < 4; ++i)
            af[i] = *(const bf16x8*)&bufA[(wr * 64 + i * 16 + qr) * 32 + gx8];
#pragma unroll
        for (int j = 0; j < 4; ++j)
            bfr[j] = *(const bf16x8*)&bufB[(wc * 64 + j * 16 + qr) * 32 + gx8];
#pragma unroll
        for (int i = 0; i < 4; ++i)
#pragma unroll
            for (int j = 0; j < 4; ++j)
                acc[i][j] = MFMA16(bfr[j], af[i], acc[i][j]);   // swapped!
        if (more) asm volatile("s_waitcnt vmcnt(3)" ::: "memory");
        else      asm volatile("s_waitcnt vmcnt(0)" ::: "memory");
        __builtin_amdgcn_s_barrier();
        __builtin_amdgcn_sched_barrier(0);
        cur = cur == 2 ? 0 : cur + 1;
        sb  = sb  == 2 ? 0 : sb  + 1;
    }
#undef STAGE3

#pragma unroll
    for (int i = 0; i < 4; ++i) {
        const int row = row0 + wr * 64 + i * 16 + qr;
#pragma unroll
        for (int j = 0; j < 4; ++j) {
            const int col = col0 + wc * 64 + j * 16 + g * 4;
            const size_t idx = (size_t)row * N + col;
            bf16 tmp[4];
            if (EPI == 3) {
                const s16x4 rv4 = *(const s16x4*)(res + idx);
#pragma unroll
                for (int r = 0; r < 4; ++r) {
                    bf16 ub; *(short*)&ub = rv4[r];
                    const float uv = (float)ub;
                    tmp[r] = (bf16)(uv / (1.f + __expf(-uv)) * acc[i][j][r]);
                }
            } else {
#pragma unroll
                for (int r = 0; r < 4; ++r) tmp[r] = (bf16)acc[i][j][r];
            }
            *(s16x4*)(C + idx) = *(s16x4*)tmp;
        }
    }
}

// ---------------------------------------------------------------------------
// Windowed-ALiBi GQA flash attention.  Round 8: single-barrier 3-buffer
// pipeline (exact gemm2 ledger): stage tile it+2 at top, compute tile it,
// vmcnt(2) retires tile it+1, ONE barrier.  Compute body unchanged.
// ---------------------------------------------------------------------------
__global__ __launch_bounds__(256)
void attn_kernel(const bf16* __restrict__ qn, const bf16* __restrict__ kn,
                 const bf16* __restrict__ vt, bf16* __restrict__ aout) {
    __shared__ bf16 SH[3 * 4096];      // buf: K [32 key][64 hd] | V [64 d][32 key]
    const int t = threadIdx.x, wv = t >> 6, ln = t & 63;
    const int qr = ln & 15, g = ln >> 4;
    const int h = blockIdx.y, b = blockIdx.z, kvh = h >> 1;
    const int q0blk = blockIdx.x * 64;
    const int qa = q0blk + wv * 16 + qr;
    const float slope = exp2f(-0.5f * (float)(h + 1));

    const bf16* qrow = qn + ((size_t)(b * 2048 + qa)) * 1024 + h * 64;
    const bf16x8 qb0 = *(const bf16x8*)(qrow + g * 8);
    const bf16x8 qb1 = *(const bf16x8*)(qrow + 32 + g * 8);

    const bf16* kbase = kn + (size_t)b * 2048 * 512 + kvh * 64;
    const bf16* vbase = vt + ((size_t)(b * 8 + kvh) * 64) * 2048;
    const int krow_l = t >> 3;
    const int kcsrc  = (t & 7) ^ ((t >> 3) & 7);
    const int vd     = t >> 2;
    const int vcsrc  = (t & 3) ^ ((t >> 2) & 3);
    const bf16* kgsrc = kbase + kcsrc * 8;
    const bf16* vgsrc = vbase + (size_t)vd * 2048;
    bf16* lK0 = SH + wv * 512;
    bf16* lV0 = SH + 2048 + wv * 512;

#define STAGE_T(kts, bi)                                           \
    do {                                                           \
        int ksrc = (kts) + krow_l;                                 \
        ksrc = ksrc > 2047 ? 2047 : ksrc;                          \
        gload_lds16(kgsrc + (size_t)ksrc * 512, lK0 + (bi) * 4096);\
        int vsrc = (kts) + vcsrc * 8;                              \
        vsrc = vsrc > 2040 ? 2040 : vsrc;                          \
        gload_lds16(vgsrc + vsrc, lV0 + (bi) * 4096);              \
    } while (0)

    STAGE_T(q0blk, 0);
    STAGE_T(q0blk + 32, 1);
    asm volatile("s_waitcnt vmcnt(2)" ::: "memory");
    __builtin_amdgcn_s_barrier();
    __builtin_amdgcn_sched_barrier(0);

    f32x4 o[4] = {};
    float mrun = -1e29f, lsum = 0.f;
    int cur = 0, sb = 2;

    for (int it = 0; it < 18; ++it) {
        const int kt = q0blk + it * 32;
        const bool more = (it + 2) < 18;
        if (more) STAGE_T(kt + 64, sb);
        const bf16* Kb = SH + cur * 4096;
        const bf16* Vb = Kb + 2048;

        f32x4 sc[2] = {f32x4{0, 0, 0, 0}, f32x4{0, 0, 0, 0}};
#pragma unroll
        for (int ks = 0; ks < 2; ++ks) {
            const int lrow = ks * 16 + qr;
            const int sw = (lrow & 7) * 8;
            sc[ks] = MFMA16(*(const bf16x8*)&Kb[lrow * 64 + (((g) * 8) ^ sw)],        qb0, sc[ks]);
            sc[ks] = MFMA16(*(const bf16x8*)&Kb[lrow * 64 + (((4 + g) * 8) ^ sw)],    qb1, sc[ks]);
        }
        float s[2][4], p[2][4];
        float tmax = -1e30f;
#pragma unroll
        for (int ks = 0; ks < 2; ++ks)
#pragma unroll
            for (int r = 0; r < 4; ++r) {
                const int key = kt + ks * 16 + g * 4 + r;
                const int dist = key - qa;
                const bool valid = (dist >= 0) && (dist <= 512) && (key < 2048);
                const float sv = valid ? sc[ks][r] * 0.125f - slope * (float)dist : -1e30f;
                s[ks][r] = sv;
                tmax = fmaxf(tmax, sv);
            }
        tmax = fmaxf(tmax, __shfl_xor(tmax, 16));
        tmax = fmaxf(tmax, __shfl_xor(tmax, 32));
        const float mnew = fmaxf(mrun, tmax);
        const float alpha = __expf(mrun - mnew);
        mrun = mnew;
        float ps = 0.f;
#pragma unroll
        for (int ks = 0; ks < 2; ++ks)
#pragma unroll
            for (int r = 0; r < 4; ++r) { p[ks][r] = __expf(s[ks][r] - mnew); ps += p[ks][r]; }
        lsum = lsum * alpha + ps;
#pragma unroll
        for (int fd = 0; fd < 4; ++fd) o[fd] *= alpha;

        bf16x8 pb;
#pragma unroll
        for (int j = 0; j < 8; ++j) {
            const int srcl = (((2 * g + (j >> 2)) & 3) << 4) | qr;
            const float v0 = __shfl(p[0][j & 3], srcl);
            const float v1 = __shfl(p[1][j & 3], srcl);
            pb[j] = (bf16)((g & 2) ? v1 : v0);
        }
#pragma unroll
        for (int fd = 0; fd < 4; ++fd) {
            const int d = fd * 16 + qr;
            const bf16x8 va = *(const bf16x8*)&Vb[d * 32 + ((g ^ (d & 3)) * 8)];
            o[fd] = MFMA16(va, pb, o[fd]);
        }

        if (more) asm volatile("s_waitcnt vmcnt(2)" ::: "memory");
        else      asm volatile("s_waitcnt vmcnt(0)" ::: "memory");
        __builtin_amdgcn_s_barrier();
        __builtin_amdgcn_sched_barrier(0);
        cur = cur == 2 ? 0 : cur + 1;
        sb  = sb  == 2 ? 0 : sb  + 1;
    }
#undef STAGE_T

    float lt = lsum + __shfl_xor(lsum, 16);
    lt += __shfl_xor(lt, 32);
    lt = fmaxf(lt, 1e-30f);
    const float inv = 1.f / lt;
    bf16* orow = aout + ((size_t)(b * 2048 + qa)) * 1024 + h * 64;
#pragma unroll
    for (int fd = 0; fd < 4; ++fd) {
        bf16 tmp[4];
#pragma unroll
        for (int r = 0; r < 4; ++r) tmp[r] = (bf16)(o[fd][r] * inv);
        *(s16x4*)(orow + fd * 16 + g * 4) = *(s16x4*)tmp;
    }
}

// ---------------------------------------------------------------------------
extern "C" void kernel_launch(void* const* d_in, const int* in_sizes, int n_in,
                              void* d_out, int out_size, void* d_ws, size_t ws_size,
                              hipStream_t stream) {
    int* flag = (int*)d_ws;
    bf16* base = (bf16*)d_ws + 64;
    bf16* h    = base;                // 4096*1024  (reused as h2)
    bf16* q    = h + 4194304;         // 4096*1024  (x1 after attn)
    bf16* kbuf = q + 4194304;         // 4096*512   (split-K partial base later)
    bf16* vtb  = kbuf + 2097152;      // 2*8*64*2048
    bf16* aout = vtb + 2097152;       // 4096*1024  (kbuf..aout = 2x4194304 span)
    bf16* u    = aout + 4194304;      // 4096*4096  (reused as act)
    bf16* wcv  = u + 16777216;        // 15728640 converted weights (contiguous)

    bf16* woc = wcv + 2097152;
    bf16* w1c = wcv + 3145728;
    bf16* w3c = wcv + 7340032;
    bf16* w2c = wcv + 11534336;

    const dim3 blk(512);
    sniff_kernel<<<1, 256, 0, stream>>>((const unsigned short*)d_in[0], flag);
    convert_all_kernel<<<15360, 256, 0, stream>>>(
        d_in[1], d_in[2], d_in[3], d_in[4], d_in[9], d_in[11], d_in[10], wcv, flag);

    ln_kernel<<<4096, 128, 0, stream>>>(d_in[0], d_in[7], h, 1024, 1e-5f, flag, 1, 1);
    // fused QKV: B = [wq;wk;wv] rows, N=2048.  EPI4: Cout=q, res=kbuf, scale=vtb
    gemm2<4, 3, 0, 0><<<dim3(16, 32), blk, 0, stream>>>(h, wcv, q, kbuf, vtb, 4096, 2048, 1024, flag, 0, 0);
    ln_kernel<<<4096, 128, 0, stream>>>(q, d_in[5], q, 1024, 1e-6f, flag, 0, 1);
    ln_kernel<<<4096, 128, 0, stream>>>(kbuf, d_in[6], kbuf, 512, 1e-6f, flag, 0, 1);
    attn_kernel<<<dim3(32, 16, 2), dim3(256), 0, stream>>>(q, kbuf, vtb, aout);
    // x1 = x + (aout@wo^T)*attn_scale  -> q (bf16)
    gemm2<1, 3, 1, 0><<<dim3(8, 32), blk, 0, stream>>>(aout, woc, q, d_in[0], d_in[12], 4096, 1024, 1024, flag, 1, 0);
    ln_kernel<<<4096, 128, 0, stream>>>(q, d_in[8], h, 1024, 1e-5f, flag, 0, 1);
    gemm3<0><<<dim3(32, 16), blk, 0, stream>>>(h, w1c, u, nullptr, 4096, 4096, 1024);
    gemm3<3><<<dim3(32, 16), blk, 0, stream>>>(h, w3c, u, u,       4096, 4096, 1024);
    // w2 split-K=2: partials (bf16) -> kbuf span, then reduce -> d_out
    gemm2<0, 5, 1, 1><<<dim3(8, 32, 2), blk, 0, stream>>>(u, w2c, kbuf, nullptr, nullptr, 4096, 1024, 4096, flag, 0, 0);
    reduce_k<<<2048, 256, 0, stream>>>(kbuf, q, d_in[13], d_out, flag);
}

// Round 9
// 262.174 us; speedup vs baseline: 1.2905x; 1.0189x over previous
//
#include <hip/hip_runtime.h>

// ---------------------------------------------------------------------------
// CodecTransformerLayer on MI355X (gfx950).  fp32 inputs (sniff-confirmed),
// bf16 internal compute.  Round 9: w1+w3 fused into one dual-B GEMM
// (shared A staging, silu on fp32 accumulators, no u round-trip, XCD
// swizzle).  Everything else unchanged from round 8.
// B=2 S=2048 D=1024 H=16 KVH=8 hd=64 HIDDEN=4096 WINDOW=512
// ---------------------------------------------------------------------------

typedef __bf16 bf16;
typedef __attribute__((ext_vector_type(8))) __bf16 bf16x8;
typedef __attribute__((ext_vector_type(4))) float f32x4;
typedef __attribute__((ext_vector_type(4))) short s16x4;

#define MFMA16(a, b, c) __builtin_amdgcn_mfma_f32_16x16x32_bf16(a, b, c, 0, 0, 0)

__device__ __forceinline__ void gload_lds16(const bf16* g, bf16* l) {
    __builtin_amdgcn_global_load_lds(
        (const __attribute__((address_space(1))) unsigned int*)g,
        (__attribute__((address_space(3))) unsigned int*)l, 16, 0, 0);
}

// ---------------------------------------------------------------------------
__global__ void sniff_kernel(const unsigned short* __restrict__ x, int* __restrict__ flag) {
    __shared__ int s;
    if (threadIdx.x == 0) s = 0;
    __syncthreads();
    int bad = 0;
#pragma unroll
    for (int i = 0; i < 16; ++i) {
        const unsigned short u = x[threadIdx.x * 16 + i];
        const int e = (u >> 7) & 0xFF;
        if (e >= 135) bad = 1;
    }
    if (bad) atomicOr(&s, 1);
    __syncthreads();
    if (threadIdx.x == 0) flag[0] = s;
}

// ---------------------------------------------------------------------------
// Weight gather -> contiguous bf16.  seg map (elements):
// wq[0) wk[1048576) wv[1572864) wo[2097152) w1[3145728) w3[7340032)
// w2[11534336) end 15728640
// ---------------------------------------------------------------------------
__global__ void convert_all_kernel(const void* __restrict__ wq, const void* __restrict__ wk,
                                   const void* __restrict__ wv, const void* __restrict__ wo,
                                   const void* __restrict__ w1, const void* __restrict__ w3,
                                   const void* __restrict__ w2, bf16* __restrict__ dst,
                                   const int* __restrict__ flag) {
    const long e = ((long)blockIdx.x * 256 + threadIdx.x) * 4;
    const void* src; long off;
    if      (e < 1048576)  { src = wq; off = 0; }
    else if (e < 1572864)  { src = wk; off = 1048576; }
    else if (e < 2097152)  { src = wv; off = 1572864; }
    else if (e < 3145728)  { src = wo; off = 2097152; }
    else if (e < 7340032)  { src = w1; off = 3145728; }
    else if (e < 11534336) { src = w3; off = 7340032; }
    else                   { src = w2; off = 11534336; }
    if (flag[0] != 0) {
        const f32x4 v = *(const f32x4*)((const float*)src + (e - off));
        bf16 tmp[4];
#pragma unroll
        for (int j = 0; j < 4; ++j) tmp[j] = (bf16)v[j];
        *(s16x4*)(dst + e) = *(s16x4*)tmp;
    } else {
        *(s16x4*)(dst + e) = *(const s16x4*)((const short*)src + (e - off));
    }
}

// ---------------------------------------------------------------------------
// LayerNorm over last dim W (1024 or 512), one 128-thread block per row.
// ---------------------------------------------------------------------------
__global__ void ln_kernel(const void* __restrict__ in, const void* __restrict__ w,
                          bf16* __restrict__ out, int W, float eps,
                          const int* __restrict__ flag, int in_flv, int w_flv) {
    const int row = blockIdx.x, t = threadIdx.x;
    const int nch = W >> 3;
    const bool act = t < nch;
    const bool f32 = flag[0] != 0;
    float v[8];
    float s = 0.f, s2 = 0.f;
    if (act) {
        if (in_flv && f32) {
            const float* rp = (const float*)in + (size_t)row * W + t * 8;
            const f32x4 a = *(const f32x4*)rp, b = *(const f32x4*)(rp + 4);
#pragma unroll
            for (int j = 0; j < 4; ++j) { v[j] = a[j]; v[4 + j] = b[j]; }
        } else {
            const bf16x8 xv = *(const bf16x8*)((const bf16*)in + (size_t)row * W + t * 8);
#pragma unroll
            for (int j = 0; j < 8; ++j) v[j] = (float)xv[j];
        }
#pragma unroll
        for (int j = 0; j < 8; ++j) { s += v[j]; s2 += v[j] * v[j]; }
    }
#pragma unroll
    for (int off = 32; off; off >>= 1) { s += __shfl_xor(s, off); s2 += __shfl_xor(s2, off); }
    __shared__ float red[4];
    if ((t & 63) == 0) { red[(t >> 6) * 2] = s; red[(t >> 6) * 2 + 1] = s2; }
    __syncthreads();
    const float fs = red[0] + red[2], fs2 = red[1] + red[3];
    const float inw = 1.f / (float)W;
    const float mean = fs * inw;
    const float var = fs2 * inw - mean * mean;
    const float rstd = rsqrtf(var + eps);
    if (act) {
        float wv8[8];
        if (w_flv && f32) {
            const float* wp = (const float*)w + t * 8;
            const f32x4 a = *(const f32x4*)wp, b = *(const f32x4*)(wp + 4);
#pragma unroll
            for (int j = 0; j < 4; ++j) { wv8[j] = a[j]; wv8[4 + j] = b[j]; }
        } else {
            const bf16x8 ww = *(const bf16x8*)((const bf16*)w + t * 8);
#pragma unroll
            for (int j = 0; j < 8; ++j) wv8[j] = (float)ww[j];
        }
        bf16x8 ov;
#pragma unroll
        for (int j = 0; j < 8; ++j) ov[j] = (bf16)((v[j] - mean) * rstd * wv8[j]);
        *(bf16x8*)(out + (size_t)row * W + t * 8) = ov;
    }
}

// ---------------------------------------------------------------------------
// Split-K reduce: out = x1 + (p0+p1)*scale[col].  p bf16 [2][4096][1024].
// ---------------------------------------------------------------------------
__global__ void reduce_k(const bf16* __restrict__ p, const bf16* __restrict__ x1,
                         const void* __restrict__ scale, void* __restrict__ out,
                         const int* __restrict__ flag) {
    const bool f32 = flag[0] != 0;
    const size_t i8 = ((size_t)blockIdx.x * 256 + threadIdx.x) * 8;
    const int col = (int)(i8 & 1023);
    const bf16x8 a = *(const bf16x8*)(p + i8);
    const bf16x8 b = *(const bf16x8*)(p + 4194304 + i8);
    const bf16x8 r = *(const bf16x8*)(x1 + i8);
    float sc8[8];
    if (f32) {
        const f32x4 s0 = *(const f32x4*)((const float*)scale + col);
        const f32x4 s1 = *(const f32x4*)((const float*)scale + col + 4);
#pragma unroll
        for (int j = 0; j < 4; ++j) { sc8[j] = s0[j]; sc8[4 + j] = s1[j]; }
    } else {
        const bf16x8 sb = *(const bf16x8*)((const bf16*)scale + col);
#pragma unroll
        for (int j = 0; j < 8; ++j) sc8[j] = (float)sb[j];
    }
    float o[8];
#pragma unroll
    for (int j = 0; j < 8; ++j)
        o[j] = (float)r[j] + ((float)a[j] + (float)b[j]) * sc8[j];
    if (f32) {
        f32x4 o0, o1;
#pragma unroll
        for (int j = 0; j < 4; ++j) { o0[j] = o[j]; o1[j] = o[4 + j]; }
        *(f32x4*)((float*)out + i8) = o0;
        *(f32x4*)((float*)out + i8 + 4) = o1;
    } else {
        bf16x8 ov;
#pragma unroll
        for (int j = 0; j < 8; ++j) ov[j] = (bf16)o[j];
        *(bf16x8*)((bf16*)out + i8) = ov;
    }
}

// ---------------------------------------------------------------------------
// Pipelined GEMM  C[M,N] = A[M,K] * B[N,K]^T.  128x128 tile, BK=32, 8 waves
// (2Mx4N), NBUF-deep counted-vmcnt pipeline, chunk-XOR LDS swizzle.
// SWZ=1: bijective XCD block remap.  SPLITK=1: blockIdx.z selects K half.
// Epilogues: 0 plain; 1 res+acc*scale[col]; 3 silu(res)*acc; 4 QKV split.
// ---------------------------------------------------------------------------
template <int EPI, int NBUF, int SWZ, int SPLITK>
__global__ __launch_bounds__(512, 4)
void gemm2(const bf16* __restrict__ A, const bf16* __restrict__ B,
           void* __restrict__ Cout, const void* __restrict__ res,
           const void* __restrict__ scale, int M, int N, int K,
           const int* __restrict__ flag, int res_flv, int out_flv) {
    __shared__ bf16 LDS[NBUF * 8192];
    const bool f32 = flag[0] != 0;
    const int t = threadIdx.x;
    const int wv = t >> 6, ln = t & 63;
    const int qr = ln & 15, g = ln >> 4;
    const int wr = wv >> 2, wc = wv & 3;
    int bx = blockIdx.x, by = blockIdx.y;
    if (SWZ) {
        const int bid = by * gridDim.x + bx;
        const int g8 = bid & 7, m = bid >> 3;
        bx = m % gridDim.x;
        by = g8 + 8 * (m / gridDim.x);
    }
    const int row0 = by * 128, col0 = bx * 128;

    const int Koff = SPLITK ? (int)blockIdx.z * (K >> 1) : 0;
    const int Keff = SPLITK ? (K >> 1) : K;
    if (SPLITK) Cout = (void*)((bf16*)Cout + (size_t)blockIdx.z * ((size_t)M * N));

    f32x4 acc[4][2] = {};

    const int cx = ((t & 3) ^ ((t >> 2) & 3)) * 8;
    const bf16* aSrc = A + (size_t)(row0 + (t >> 2)) * K + Koff + cx;
    const bf16* bSrc = B + (size_t)(col0 + (t >> 2)) * K + Koff + cx;
    const int gx8 = (g ^ (qr & 3)) * 8;              // swizzled read chunk
    const int NIT = Keff >> 5;

#define STAGE(bi, k0)                                              \
    do {                                                           \
        bf16* lb = LDS + (bi) * 8192 + wv * 512;                   \
        gload_lds16(aSrc + (k0), lb);                              \
        gload_lds16(bSrc + (k0), lb + 4096);                       \
    } while (0)

#pragma unroll
    for (int pb = 0; pb < NBUF - 1; ++pb) STAGE(pb, pb * 32);
    if constexpr (NBUF == 3) asm volatile("s_waitcnt vmcnt(2)" ::: "memory");
    else                     asm volatile("s_waitcnt vmcnt(6)" ::: "memory");
    __builtin_amdgcn_s_barrier();
    __builtin_amdgcn_sched_barrier(0);

    int cur = 0, sb = NBUF - 1;
    for (int it = 0; it < NIT; ++it) {
        const bool more = (it + NBUF - 1) < NIT;
        if (more) STAGE(sb, (it + NBUF - 1) * 32);
        const bf16* bufA = LDS + cur * 8192;
        const bf16* bufB = bufA + 4096;
        bf16x8 af[4], bfr[2];
#pragma unroll
        for (int i = 0; i < 4; ++i)
            af[i] = *(const bf16x8*)&bufA[(wr * 64 + i * 16 + qr) * 32 + gx8];
#pragma unroll
        for (int j = 0; j < 2; ++j)
            bfr[j] = *(const bf16x8*)&bufB[(wc * 32 + j * 16 + qr) * 32 + gx8];
#pragma unroll
        for (int i = 0; i < 4; ++i)
#pragma unroll
            for (int j = 0; j < 2; ++j)
                acc[i][j] = MFMA16(af[i], bfr[j], acc[i][j]);
        if (more) {
            if constexpr (NBUF == 3) asm volatile("s_waitcnt vmcnt(2)" ::: "memory");
            else                     asm volatile("s_waitcnt vmcnt(6)" ::: "memory");
        } else {
            asm volatile("s_waitcnt vmcnt(0)" ::: "memory");
        }
        __builtin_amdgcn_s_barrier();
        __builtin_amdgcn_sched_barrier(0);
        cur = cur + 1 == NBUF ? 0 : cur + 1;
        sb  = sb + 1 == NBUF ? 0 : sb + 1;
    }
#undef STAGE

#pragma unroll
    for (int i = 0; i < 4; ++i) {
#pragma unroll
        for (int j = 0; j < 2; ++j) {
            const int rr0 = row0 + wr * 64 + i * 16 + g * 4;  // C/D row=(l>>4)*4+r
            const int cc  = col0 + wc * 32 + j * 16 + qr;     //     col=l&15
            if (EPI == 4) {
                if (cc < 1024) {                 // q
#pragma unroll
                    for (int r = 0; r < 4; ++r)
                        ((bf16*)Cout)[(size_t)(rr0 + r) * 1024 + cc] = (bf16)acc[i][j][r];
                } else if (cc < 1536) {          // k
#pragma unroll
                    for (int r = 0; r < 4; ++r)
                        ((bf16*)res)[(size_t)(rr0 + r) * 512 + (cc - 1024)] = (bf16)acc[i][j][r];
                } else {                         // v transposed bf16: Vt[b][kvh][d][s]
                    const int kv = cc - 1536, kvh = kv >> 6, d = kv & 63;
                    const int bb = rr0 >> 11, s0 = rr0 & 2047;
                    bf16 tmp[4];
#pragma unroll
                    for (int r = 0; r < 4; ++r) tmp[r] = (bf16)acc[i][j][r];
                    *(s16x4*)((bf16*)scale + (((size_t)bb * 8 + kvh) * 64 + d) * 2048 + s0) = *(s16x4*)tmp;
                }
            } else {
                float scv = 0.f;
                if (EPI == 1)
                    scv = f32 ? ((const float*)scale)[cc] : (float)((const bf16*)scale)[cc];
#pragma unroll
                for (int r = 0; r < 4; ++r) {
                    const size_t idx = (size_t)(rr0 + r) * N + cc;
                    float vv = acc[i][j][r];
                    if (EPI == 1) {
                        const float rv = (res_flv && f32) ? ((const float*)res)[idx]
                                                          : (float)((const bf16*)res)[idx];
                        vv = rv + vv * scv;
                    }
                    if (EPI == 3) {
                        const float uv = (float)((const bf16*)res)[idx];
                        vv = uv / (1.f + __expf(-uv)) * vv;
                    }
                    if (out_flv && f32) ((float*)Cout)[idx] = vv;
                    else                ((bf16*)Cout)[idx] = (bf16)vv;
                }
            }
        }
    }
}

// ---------------------------------------------------------------------------
// gemm_w13: fused SwiGLU up-projection.  C = silu(A@B1^T) * (A@B3^T).
// 128x128 tile, BK=32, 8 waves (2Mx4N), 3-buffer counted-vmcnt pipeline
// (3 loads/tile -> vmcnt(3)), shared A staging for both B's, chunk-XOR
// swizzle, bijective XCD remap.  silu applied to fp32 accumulators.
// LDS 72 KB -> 2 blocks/CU.
// ---------------------------------------------------------------------------
__global__ __launch_bounds__(512, 4)
void gemm_w13(const bf16* __restrict__ A, const bf16* __restrict__ B1,
              const bf16* __restrict__ B3, bf16* __restrict__ C,
              int M, int N, int K) {
    __shared__ bf16 LDS[3 * 12288];      // per buf: A 8KB | B1 8KB | B3 8KB
    const int t = threadIdx.x;
    const int wv = t >> 6, ln = t & 63;
    const int qr = ln & 15, g = ln >> 4;
    const int wr = wv >> 2, wc = wv & 3;
    int bx = blockIdx.x, by = blockIdx.y;
    {   // bijective XCD remap (grid 32x32)
        const int bid = by * gridDim.x + bx;
        const int g8 = bid & 7, m = bid >> 3;
        bx = m % gridDim.x;
        by = g8 + 8 * (m / gridDim.x);
    }
    const int row0 = by * 128, col0 = bx * 128;

    f32x4 acc1[4][2] = {}, acc3[4][2] = {};

    const int cx = ((t & 3) ^ ((t >> 2) & 3)) * 8;
    const bf16* aSrc  = A  + (size_t)(row0 + (t >> 2)) * K + cx;
    const bf16* b1Src = B1 + (size_t)(col0 + (t >> 2)) * K + cx;
    const bf16* b3Src = B3 + (size_t)(col0 + (t >> 2)) * K + cx;
    const int gx8 = (g ^ (qr & 3)) * 8;
    const int NIT = K >> 5;

#define STAGEW(bi, k0)                                             \
    do {                                                           \
        bf16* lb = LDS + (bi) * 12288 + wv * 512;                  \
        gload_lds16(aSrc + (k0), lb);                              \
        gload_lds16(b1Src + (k0), lb + 4096);                      \
        gload_lds16(b3Src + (k0), lb + 8192);                      \
    } while (0)

    STAGEW(0, 0);
    STAGEW(1, 32);
    asm volatile("s_waitcnt vmcnt(3)" ::: "memory");
    __builtin_amdgcn_s_barrier();
    __builtin_amdgcn_sched_barrier(0);

    int cur = 0, sb = 2;
    for (int it = 0; it < NIT; ++it) {
        const bool more = (it + 2) < NIT;
        if (more) STAGEW(sb, (it + 2) * 32);
        const bf16* bufA  = LDS + cur * 12288;
        const bf16* bufB1 = bufA + 4096;
        const bf16* bufB3 = bufA + 8192;
        bf16x8 af[4], b1f[2], b3f[2];
#pragma unroll
        for (int i = 0; i < 4; ++i)
            af[i] = *(const bf16x8*)&bufA[(wr * 64 + i * 16 + qr) * 32 + gx8];
#pragma unroll
        for (int j = 0; j < 2; ++j) {
            b1f[j] = *(const bf16x8*)&bufB1[(wc * 32 + j * 16 + qr) * 32 + gx8];
            b3f[j] = *(const bf16x8*)&bufB3[(wc * 32 + j * 16 + qr) * 32 + gx8];
        }
#pragma unroll
        for (int i = 0; i < 4; ++i)
#pragma unroll
            for (int j = 0; j < 2; ++j) {
                acc1[i][j] = MFMA16(af[i], b1f[j], acc1[i][j]);
                acc3[i][j] = MFMA16(af[i], b3f[j], acc3[i][j]);
            }
        if (more) asm volatile("s_waitcnt vmcnt(3)" ::: "memory");
        else      asm volatile("s_waitcnt vmcnt(0)" ::: "memory");
        __builtin_amdgcn_s_barrier();
        __builtin_amdgcn_sched_barrier(0);
        cur = cur == 2 ? 0 : cur + 1;
        sb  = sb  == 2 ? 0 : sb  + 1;
    }
#undef STAGEW

#pragma unroll
    for (int i = 0; i < 4; ++i) {
#pragma unroll
        for (int j = 0; j < 2; ++j) {
            const int rr0 = row0 + wr * 64 + i * 16 + g * 4;
            const int cc  = col0 + wc * 32 + j * 16 + qr;
#pragma unroll
            for (int r = 0; r < 4; ++r) {
                const float u1 = acc1[i][j][r];
                const float u3 = acc3[i][j][r];
                C[(size_t)(rr0 + r) * N + cc] = (bf16)(u1 / (1.f + __expf(-u1)) * u3);
            }
        }
    }
}

// ---------------------------------------------------------------------------
// Windowed-ALiBi GQA flash attention (unchanged from round 8: single-barrier
// 3-buffer counted-vmcnt pipeline, swapped QK^T, shfl P^T build).
// ---------------------------------------------------------------------------
__global__ __launch_bounds__(256)
void attn_kernel(const bf16* __restrict__ qn, const bf16* __restrict__ kn,
                 const bf16* __restrict__ vt, bf16* __restrict__ aout) {
    __shared__ bf16 SH[3 * 4096];      // buf: K [32 key][64 hd] | V [64 d][32 key]
    const int t = threadIdx.x, wv = t >> 6, ln = t & 63;
    const int qr = ln & 15, g = ln >> 4;
    const int h = blockIdx.y, b = blockIdx.z, kvh = h >> 1;
    const int q0blk = blockIdx.x * 64;
    const int qa = q0blk + wv * 16 + qr;
    const float slope = exp2f(-0.5f * (float)(h + 1));

    const bf16* qrow = qn + ((size_t)(b * 2048 + qa)) * 1024 + h * 64;
    const bf16x8 qb0 = *(const bf16x8*)(qrow + g * 8);
    const bf16x8 qb1 = *(const bf16x8*)(qrow + 32 + g * 8);

    const bf16* kbase = kn + (size_t)b * 2048 * 512 + kvh * 64;
    const bf16* vbase = vt + ((size_t)(b * 8 + kvh) * 64) * 2048;
    const int krow_l = t >> 3;
    const int kcsrc  = (t & 7) ^ ((t >> 3) & 7);
    const int vd     = t >> 2;
    const int vcsrc  = (t & 3) ^ ((t >> 2) & 3);
    const bf16* kgsrc = kbase + kcsrc * 8;
    const bf16* vgsrc = vbase + (size_t)vd * 2048;
    bf16* lK0 = SH + wv * 512;
    bf16* lV0 = SH + 2048 + wv * 512;

#define STAGE_T(kts, bi)                                           \
    do {                                                           \
        int ksrc = (kts) + krow_l;                                 \
        ksrc = ksrc > 2047 ? 2047 : ksrc;                          \
        gload_lds16(kgsrc + (size_t)ksrc * 512, lK0 + (bi) * 4096);\
        int vsrc = (kts) + vcsrc * 8;                              \
        vsrc = vsrc > 2040 ? 2040 : vsrc;                          \
        gload_lds16(vgsrc + vsrc, lV0 + (bi) * 4096);              \
    } while (0)

    STAGE_T(q0blk, 0);
    STAGE_T(q0blk + 32, 1);
    asm volatile("s_waitcnt vmcnt(2)" ::: "memory");
    __builtin_amdgcn_s_barrier();
    __builtin_amdgcn_sched_barrier(0);

    f32x4 o[4] = {};
    float mrun = -1e29f, lsum = 0.f;
    int cur = 0, sb = 2;

    for (int it = 0; it < 18; ++it) {
        const int kt = q0blk + it * 32;
        const bool more = (it + 2) < 18;
        if (more) STAGE_T(kt + 64, sb);
        const bf16* Kb = SH + cur * 4096;
        const bf16* Vb = Kb + 2048;

        f32x4 sc[2] = {f32x4{0, 0, 0, 0}, f32x4{0, 0, 0, 0}};
#pragma unroll
        for (int ks = 0; ks < 2; ++ks) {
            const int lrow = ks * 16 + qr;
            const int sw = (lrow & 7) * 8;
            sc[ks] = MFMA16(*(const bf16x8*)&Kb[lrow * 64 + (((g) * 8) ^ sw)],        qb0, sc[ks]);
            sc[ks] = MFMA16(*(const bf16x8*)&Kb[lrow * 64 + (((4 + g) * 8) ^ sw)],    qb1, sc[ks]);
        }
        float s[2][4], p[2][4];
        float tmax = -1e30f;
#pragma unroll
        for (int ks = 0; ks < 2; ++ks)
#pragma unroll
            for (int r = 0; r < 4; ++r) {
                const int key = kt + ks * 16 + g * 4 + r;
                const int dist = key - qa;
                const bool valid = (dist >= 0) && (dist <= 512) && (key < 2048);
                const float sv = valid ? sc[ks][r] * 0.125f - slope * (float)dist : -1e30f;
                s[ks][r] = sv;
                tmax = fmaxf(tmax, sv);
            }
        tmax = fmaxf(tmax, __shfl_xor(tmax, 16));
        tmax = fmaxf(tmax, __shfl_xor(tmax, 32));
        const float mnew = fmaxf(mrun, tmax);
        const float alpha = __expf(mrun - mnew);
        mrun = mnew;
        float ps = 0.f;
#pragma unroll
        for (int ks = 0; ks < 2; ++ks)
#pragma unroll
            for (int r = 0; r < 4; ++r) { p[ks][r] = __expf(s[ks][r] - mnew); ps += p[ks][r]; }
        lsum = lsum * alpha + ps;
#pragma unroll
        for (int fd = 0; fd < 4; ++fd) o[fd] *= alpha;

        bf16x8 pb;
#pragma unroll
        for (int j = 0; j < 8; ++j) {
            const int srcl = (((2 * g + (j >> 2)) & 3) << 4) | qr;
            const float v0 = __shfl(p[0][j & 3], srcl);
            const float v1 = __shfl(p[1][j & 3], srcl);
            pb[j] = (bf16)((g & 2) ? v1 : v0);
        }
#pragma unroll
        for (int fd = 0; fd < 4; ++fd) {
            const int d = fd * 16 + qr;
            const bf16x8 va = *(const bf16x8*)&Vb[d * 32 + ((g ^ (d & 3)) * 8)];
            o[fd] = MFMA16(va, pb, o[fd]);
        }

        if (more) asm volatile("s_waitcnt vmcnt(2)" ::: "memory");
        else      asm volatile("s_waitcnt vmcnt(0)" ::: "memory");
        __builtin_amdgcn_s_barrier();
        __builtin_amdgcn_sched_barrier(0);
        cur = cur == 2 ? 0 : cur + 1;
        sb  = sb  == 2 ? 0 : sb  + 1;
    }
#undef STAGE_T

    float lt = lsum + __shfl_xor(lsum, 16);
    lt += __shfl_xor(lt, 32);
    lt = fmaxf(lt, 1e-30f);
    const float inv = 1.f / lt;
    bf16* orow = aout + ((size_t)(b * 2048 + qa)) * 1024 + h * 64;
#pragma unroll
    for (int fd = 0; fd < 4; ++fd) {
        bf16 tmp[4];
#pragma unroll
        for (int r = 0; r < 4; ++r) tmp[r] = (bf16)(o[fd][r] * inv);
        *(s16x4*)(orow + fd * 16 + g * 4) = *(s16x4*)tmp;
    }
}

// ---------------------------------------------------------------------------
extern "C" void kernel_launch(void* const* d_in, const int* in_sizes, int n_in,
                              void* d_out, int out_size, void* d_ws, size_t ws_size,
                              hipStream_t stream) {
    int* flag = (int*)d_ws;
    bf16* base = (bf16*)d_ws + 64;
    bf16* h    = base;                // 4096*1024  (reused as h2)
    bf16* q    = h + 4194304;         // 4096*1024  (x1 after attn)
    bf16* kbuf = q + 4194304;         // 4096*512   (split-K partial base later)
    bf16* vtb  = kbuf + 2097152;      // 2*8*64*2048
    bf16* aout = vtb + 2097152;       // 4096*1024  (kbuf..aout = 2x4194304 span)
    bf16* u    = aout + 4194304;      // 4096*4096  (act)
    bf16* wcv  = u + 16777216;        // 15728640 converted weights (contiguous)

    bf16* woc = wcv + 2097152;
    bf16* w1c = wcv + 3145728;
    bf16* w3c = wcv + 7340032;
    bf16* w2c = wcv + 11534336;

    const dim3 blk(512);
    sniff_kernel<<<1, 256, 0, stream>>>((const unsigned short*)d_in[0], flag);
    convert_all_kernel<<<15360, 256, 0, stream>>>(
        d_in[1], d_in[2], d_in[3], d_in[4], d_in[9], d_in[11], d_in[10], wcv, flag);

    ln_kernel<<<4096, 128, 0, stream>>>(d_in[0], d_in[7], h, 1024, 1e-5f, flag, 1, 1);
    // fused QKV: B = [wq;wk;wv] rows, N=2048.  EPI4: Cout=q, res=kbuf, scale=vtb
    gemm2<4, 3, 0, 0><<<dim3(16, 32), blk, 0, stream>>>(h, wcv, q, kbuf, vtb, 4096, 2048, 1024, flag, 0, 0);
    ln_kernel<<<4096, 128, 0, stream>>>(q, d_in[5], q, 1024, 1e-6f, flag, 0, 1);
    ln_kernel<<<4096, 128, 0, stream>>>(kbuf, d_in[6], kbuf, 512, 1e-6f, flag, 0, 1);
    attn_kernel<<<dim3(32, 16, 2), dim3(256), 0, stream>>>(q, kbuf, vtb, aout);
    // x1 = x + (aout@wo^T)*attn_scale  -> q (bf16)
    gemm2<1, 3, 1, 0><<<dim3(8, 32), blk, 0, stream>>>(aout, woc, q, d_in[0], d_in[12], 4096, 1024, 1024, flag, 1, 0);
    ln_kernel<<<4096, 128, 0, stream>>>(q, d_in[8], h, 1024, 1e-5f, flag, 0, 1);
    // fused SwiGLU up: u = silu(h@w1^T) * (h@w3^T)
    gemm_w13<<<dim3(32, 32), blk, 0, stream>>>(h, w1c, w3c, u, 4096, 4096, 1024);
    // w2 split-K=2: partials (bf16) -> kbuf span, then reduce -> d_out
    gemm2<0, 5, 1, 1><<<dim3(8, 32, 2), blk, 0, stream>>>(u, w2c, kbuf, nullptr, nullptr, 4096, 1024, 4096, flag, 0, 0);
    reduce_k<<<2048, 256, 0, stream>>>(kbuf, q, d_in[13], d_out, flag);
}

// Round 10
// 248.268 us; speedup vs baseline: 1.3627x; 1.0560x over previous
//
#include <hip/hip_runtime.h>

// ---------------------------------------------------------------------------
// CodecTransformerLayer on MI355X (gfx950).  fp32 inputs (sniff-confirmed),
// bf16 internal compute.  Round 10: gemm_w13 column-ownership XCD remap
// (each XCD's B1/B3 working set = 2 MB, L2-resident; was 16 MB -> 240 MB
// refetch) + swapped-operand MFMA with vectorized s16x4 stores.
// Everything else unchanged from round 9.
// B=2 S=2048 D=1024 H=16 KVH=8 hd=64 HIDDEN=4096 WINDOW=512
// ---------------------------------------------------------------------------

typedef __bf16 bf16;
typedef __attribute__((ext_vector_type(8))) __bf16 bf16x8;
typedef __attribute__((ext_vector_type(4))) float f32x4;
typedef __attribute__((ext_vector_type(4))) short s16x4;

#define MFMA16(a, b, c) __builtin_amdgcn_mfma_f32_16x16x32_bf16(a, b, c, 0, 0, 0)

__device__ __forceinline__ void gload_lds16(const bf16* g, bf16* l) {
    __builtin_amdgcn_global_load_lds(
        (const __attribute__((address_space(1))) unsigned int*)g,
        (__attribute__((address_space(3))) unsigned int*)l, 16, 0, 0);
}

// ---------------------------------------------------------------------------
__global__ void sniff_kernel(const unsigned short* __restrict__ x, int* __restrict__ flag) {
    __shared__ int s;
    if (threadIdx.x == 0) s = 0;
    __syncthreads();
    int bad = 0;
#pragma unroll
    for (int i = 0; i < 16; ++i) {
        const unsigned short u = x[threadIdx.x * 16 + i];
        const int e = (u >> 7) & 0xFF;
        if (e >= 135) bad = 1;
    }
    if (bad) atomicOr(&s, 1);
    __syncthreads();
    if (threadIdx.x == 0) flag[0] = s;
}

// ---------------------------------------------------------------------------
// Weight gather -> contiguous bf16.  seg map (elements):
// wq[0) wk[1048576) wv[1572864) wo[2097152) w1[3145728) w3[7340032)
// w2[11534336) end 15728640
// ---------------------------------------------------------------------------
__global__ void convert_all_kernel(const void* __restrict__ wq, const void* __restrict__ wk,
                                   const void* __restrict__ wv, const void* __restrict__ wo,
                                   const void* __restrict__ w1, const void* __restrict__ w3,
                                   const void* __restrict__ w2, bf16* __restrict__ dst,
                                   const int* __restrict__ flag) {
    const long e = ((long)blockIdx.x * 256 + threadIdx.x) * 4;
    const void* src; long off;
    if      (e < 1048576)  { src = wq; off = 0; }
    else if (e < 1572864)  { src = wk; off = 1048576; }
    else if (e < 2097152)  { src = wv; off = 1572864; }
    else if (e < 3145728)  { src = wo; off = 2097152; }
    else if (e < 7340032)  { src = w1; off = 3145728; }
    else if (e < 11534336) { src = w3; off = 7340032; }
    else                   { src = w2; off = 11534336; }
    if (flag[0] != 0) {
        const f32x4 v = *(const f32x4*)((const float*)src + (e - off));
        bf16 tmp[4];
#pragma unroll
        for (int j = 0; j < 4; ++j) tmp[j] = (bf16)v[j];
        *(s16x4*)(dst + e) = *(s16x4*)tmp;
    } else {
        *(s16x4*)(dst + e) = *(const s16x4*)((const short*)src + (e - off));
    }
}

// ---------------------------------------------------------------------------
// LayerNorm over last dim W (1024 or 512), one 128-thread block per row.
// ---------------------------------------------------------------------------
__global__ void ln_kernel(const void* __restrict__ in, const void* __restrict__ w,
                          bf16* __restrict__ out, int W, float eps,
                          const int* __restrict__ flag, int in_flv, int w_flv) {
    const int row = blockIdx.x, t = threadIdx.x;
    const int nch = W >> 3;
    const bool act = t < nch;
    const bool f32 = flag[0] != 0;
    float v[8];
    float s = 0.f, s2 = 0.f;
    if (act) {
        if (in_flv && f32) {
            const float* rp = (const float*)in + (size_t)row * W + t * 8;
            const f32x4 a = *(const f32x4*)rp, b = *(const f32x4*)(rp + 4);
#pragma unroll
            for (int j = 0; j < 4; ++j) { v[j] = a[j]; v[4 + j] = b[j]; }
        } else {
            const bf16x8 xv = *(const bf16x8*)((const bf16*)in + (size_t)row * W + t * 8);
#pragma unroll
            for (int j = 0; j < 8; ++j) v[j] = (float)xv[j];
        }
#pragma unroll
        for (int j = 0; j < 8; ++j) { s += v[j]; s2 += v[j] * v[j]; }
    }
#pragma unroll
    for (int off = 32; off; off >>= 1) { s += __shfl_xor(s, off); s2 += __shfl_xor(s2, off); }
    __shared__ float red[4];
    if ((t & 63) == 0) { red[(t >> 6) * 2] = s; red[(t >> 6) * 2 + 1] = s2; }
    __syncthreads();
    const float fs = red[0] + red[2], fs2 = red[1] + red[3];
    const float inw = 1.f / (float)W;
    const float mean = fs * inw;
    const float var = fs2 * inw - mean * mean;
    const float rstd = rsqrtf(var + eps);
    if (act) {
        float wv8[8];
        if (w_flv && f32) {
            const float* wp = (const float*)w + t * 8;
            const f32x4 a = *(const f32x4*)wp, b = *(const f32x4*)(wp + 4);
#pragma unroll
            for (int j = 0; j < 4; ++j) { wv8[j] = a[j]; wv8[4 + j] = b[j]; }
        } else {
            const bf16x8 ww = *(const bf16x8*)((const bf16*)w + t * 8);
#pragma unroll
            for (int j = 0; j < 8; ++j) wv8[j] = (float)ww[j];
        }
        bf16x8 ov;
#pragma unroll
        for (int j = 0; j < 8; ++j) ov[j] = (bf16)((v[j] - mean) * rstd * wv8[j]);
        *(bf16x8*)(out + (size_t)row * W + t * 8) = ov;
    }
}

// ---------------------------------------------------------------------------
// Split-K reduce: out = x1 + (p0+p1)*scale[col].  p bf16 [2][4096][1024].
// ---------------------------------------------------------------------------
__global__ void reduce_k(const bf16* __restrict__ p, const bf16* __restrict__ x1,
                         const void* __restrict__ scale, void* __restrict__ out,
                         const int* __restrict__ flag) {
    const bool f32 = flag[0] != 0;
    const size_t i8 = ((size_t)blockIdx.x * 256 + threadIdx.x) * 8;
    const int col = (int)(i8 & 1023);
    const bf16x8 a = *(const bf16x8*)(p + i8);
    const bf16x8 b = *(const bf16x8*)(p + 4194304 + i8);
    const bf16x8 r = *(const bf16x8*)(x1 + i8);
    float sc8[8];
    if (f32) {
        const f32x4 s0 = *(const f32x4*)((const float*)scale + col);
        const f32x4 s1 = *(const f32x4*)((const float*)scale + col + 4);
#pragma unroll
        for (int j = 0; j < 4; ++j) { sc8[j] = s0[j]; sc8[4 + j] = s1[j]; }
    } else {
        const bf16x8 sb = *(const bf16x8*)((const bf16*)scale + col);
#pragma unroll
        for (int j = 0; j < 8; ++j) sc8[j] = (float)sb[j];
    }
    float o[8];
#pragma unroll
    for (int j = 0; j < 8; ++j)
        o[j] = (float)r[j] + ((float)a[j] + (float)b[j]) * sc8[j];
    if (f32) {
        f32x4 o0, o1;
#pragma unroll
        for (int j = 0; j < 4; ++j) { o0[j] = o[j]; o1[j] = o[4 + j]; }
        *(f32x4*)((float*)out + i8) = o0;
        *(f32x4*)((float*)out + i8 + 4) = o1;
    } else {
        bf16x8 ov;
#pragma unroll
        for (int j = 0; j < 8; ++j) ov[j] = (bf16)o[j];
        *(bf16x8*)((bf16*)out + i8) = ov;
    }
}

// ---------------------------------------------------------------------------
// Pipelined GEMM  C[M,N] = A[M,K] * B[N,K]^T.  128x128 tile, BK=32, 8 waves
// (2Mx4N), NBUF-deep counted-vmcnt pipeline, chunk-XOR LDS swizzle.
// SWZ=1: bijective XCD block remap (row ownership).  SPLITK=1: blockIdx.z
// selects K half.  Epilogues: 0 plain; 1 res+acc*scale[col]; 3 silu(res)*acc;
// 4 QKV split.
// ---------------------------------------------------------------------------
template <int EPI, int NBUF, int SWZ, int SPLITK>
__global__ __launch_bounds__(512, 4)
void gemm2(const bf16* __restrict__ A, const bf16* __restrict__ B,
           void* __restrict__ Cout, const void* __restrict__ res,
           const void* __restrict__ scale, int M, int N, int K,
           const int* __restrict__ flag, int res_flv, int out_flv) {
    __shared__ bf16 LDS[NBUF * 8192];
    const bool f32 = flag[0] != 0;
    const int t = threadIdx.x;
    const int wv = t >> 6, ln = t & 63;
    const int qr = ln & 15, g = ln >> 4;
    const int wr = wv >> 2, wc = wv & 3;
    int bx = blockIdx.x, by = blockIdx.y;
    if (SWZ) {
        const int bid = by * gridDim.x + bx;
        const int g8 = bid & 7, m = bid >> 3;
        bx = m % gridDim.x;
        by = g8 + 8 * (m / gridDim.x);
    }
    const int row0 = by * 128, col0 = bx * 128;

    const int Koff = SPLITK ? (int)blockIdx.z * (K >> 1) : 0;
    const int Keff = SPLITK ? (K >> 1) : K;
    if (SPLITK) Cout = (void*)((bf16*)Cout + (size_t)blockIdx.z * ((size_t)M * N));

    f32x4 acc[4][2] = {};

    const int cx = ((t & 3) ^ ((t >> 2) & 3)) * 8;
    const bf16* aSrc = A + (size_t)(row0 + (t >> 2)) * K + Koff + cx;
    const bf16* bSrc = B + (size_t)(col0 + (t >> 2)) * K + Koff + cx;
    const int gx8 = (g ^ (qr & 3)) * 8;              // swizzled read chunk
    const int NIT = Keff >> 5;

#define STAGE(bi, k0)                                              \
    do {                                                           \
        bf16* lb = LDS + (bi) * 8192 + wv * 512;                   \
        gload_lds16(aSrc + (k0), lb);                              \
        gload_lds16(bSrc + (k0), lb + 4096);                       \
    } while (0)

#pragma unroll
    for (int pb = 0; pb < NBUF - 1; ++pb) STAGE(pb, pb * 32);
    if constexpr (NBUF == 3) asm volatile("s_waitcnt vmcnt(2)" ::: "memory");
    else                     asm volatile("s_waitcnt vmcnt(6)" ::: "memory");
    __builtin_amdgcn_s_barrier();
    __builtin_amdgcn_sched_barrier(0);

    int cur = 0, sb = NBUF - 1;
    for (int it = 0; it < NIT; ++it) {
        const bool more = (it + NBUF - 1) < NIT;
        if (more) STAGE(sb, (it + NBUF - 1) * 32);
        const bf16* bufA = LDS + cur * 8192;
        const bf16* bufB = bufA + 4096;
        bf16x8 af[4], bfr[2];
#pragma unroll
        for (int i = 0; i < 4; ++i)
            af[i] = *(const bf16x8*)&bufA[(wr * 64 + i * 16 + qr) * 32 + gx8];
#pragma unroll
        for (int j = 0; j < 2; ++j)
            bfr[j] = *(const bf16x8*)&bufB[(wc * 32 + j * 16 + qr) * 32 + gx8];
#pragma unroll
        for (int i = 0; i < 4; ++i)
#pragma unroll
            for (int j = 0; j < 2; ++j)
                acc[i][j] = MFMA16(af[i], bfr[j], acc[i][j]);
        if (more) {
            if constexpr (NBUF == 3) asm volatile("s_waitcnt vmcnt(2)" ::: "memory");
            else                     asm volatile("s_waitcnt vmcnt(6)" ::: "memory");
        } else {
            asm volatile("s_waitcnt vmcnt(0)" ::: "memory");
        }
        __builtin_amdgcn_s_barrier();
        __builtin_amdgcn_sched_barrier(0);
        cur = cur + 1 == NBUF ? 0 : cur + 1;
        sb  = sb + 1 == NBUF ? 0 : sb + 1;
    }
#undef STAGE

#pragma unroll
    for (int i = 0; i < 4; ++i) {
#pragma unroll
        for (int j = 0; j < 2; ++j) {
            const int rr0 = row0 + wr * 64 + i * 16 + g * 4;  // C/D row=(l>>4)*4+r
            const int cc  = col0 + wc * 32 + j * 16 + qr;     //     col=l&15
            if (EPI == 4) {
                if (cc < 1024) {                 // q
#pragma unroll
                    for (int r = 0; r < 4; ++r)
                        ((bf16*)Cout)[(size_t)(rr0 + r) * 1024 + cc] = (bf16)acc[i][j][r];
                } else if (cc < 1536) {          // k
#pragma unroll
                    for (int r = 0; r < 4; ++r)
                        ((bf16*)res)[(size_t)(rr0 + r) * 512 + (cc - 1024)] = (bf16)acc[i][j][r];
                } else {                         // v transposed bf16: Vt[b][kvh][d][s]
                    const int kv = cc - 1536, kvh = kv >> 6, d = kv & 63;
                    const int bb = rr0 >> 11, s0 = rr0 & 2047;
                    bf16 tmp[4];
#pragma unroll
                    for (int r = 0; r < 4; ++r) tmp[r] = (bf16)acc[i][j][r];
                    *(s16x4*)((bf16*)scale + (((size_t)bb * 8 + kvh) * 64 + d) * 2048 + s0) = *(s16x4*)tmp;
                }
            } else {
                float scv = 0.f;
                if (EPI == 1)
                    scv = f32 ? ((const float*)scale)[cc] : (float)((const bf16*)scale)[cc];
#pragma unroll
                for (int r = 0; r < 4; ++r) {
                    const size_t idx = (size_t)(rr0 + r) * N + cc;
                    float vv = acc[i][j][r];
                    if (EPI == 1) {
                        const float rv = (res_flv && f32) ? ((const float*)res)[idx]
                                                          : (float)((const bf16*)res)[idx];
                        vv = rv + vv * scv;
                    }
                    if (EPI == 3) {
                        const float uv = (float)((const bf16*)res)[idx];
                        vv = uv / (1.f + __expf(-uv)) * vv;
                    }
                    if (out_flv && f32) ((float*)Cout)[idx] = vv;
                    else                ((bf16*)Cout)[idx] = (bf16)vv;
                }
            }
        }
    }
}

// ---------------------------------------------------------------------------
// gemm_w13: fused SwiGLU up-projection.  C = silu(A@B1^T) * (A@B3^T).
// 128x128 tile, BK=32, 8 waves (2Mx4N), 3-buffer counted-vmcnt pipeline,
// shared A staging, chunk-XOR swizzle.
// Round 10: COLUMN-ownership XCD remap — each XCD owns 4 B-column panels
// (B1+B3 working set 2 MB, L2-resident) and streams A rows; 4 consecutive
// blocks share each A-panel.  Swapped-operand MFMA -> s16x4 stores.
// ---------------------------------------------------------------------------
__global__ __launch_bounds__(512, 4)
void gemm_w13(const bf16* __restrict__ A, const bf16* __restrict__ B1,
              const bf16* __restrict__ B3, bf16* __restrict__ C,
              int M, int N, int K) {
    __shared__ bf16 LDS[3 * 12288];      // per buf: A 8KB | B1 8KB | B3 8KB
    const int t = threadIdx.x;
    const int wv = t >> 6, ln = t & 63;
    const int qr = ln & 15, g = ln >> 4;
    const int wr = wv >> 2, wc = wv & 3;
    int bx, by;
    {   // column-ownership XCD remap (grid 32x32, bijective)
        const int bid = blockIdx.y * gridDim.x + blockIdx.x;
        const int xcd = bid & 7, m = bid >> 3;
        bx = xcd * 4 + (m & 3);          // XCD owns 4 column panels
        by = m >> 2;                     // sweeps all 32 row panels
    }
    const int row0 = by * 128, col0 = bx * 128;

    f32x4 acc1[4][2] = {}, acc3[4][2] = {};

    const int cx = ((t & 3) ^ ((t >> 2) & 3)) * 8;
    const bf16* aSrc  = A  + (size_t)(row0 + (t >> 2)) * K + cx;
    const bf16* b1Src = B1 + (size_t)(col0 + (t >> 2)) * K + cx;
    const bf16* b3Src = B3 + (size_t)(col0 + (t >> 2)) * K + cx;
    const int gx8 = (g ^ (qr & 3)) * 8;
    const int NIT = K >> 5;

#define STAGEW(bi, k0)                                             \
    do {                                                           \
        bf16* lb = LDS + (bi) * 12288 + wv * 512;                  \
        gload_lds16(aSrc + (k0), lb);                              \
        gload_lds16(b1Src + (k0), lb + 4096);                      \
        gload_lds16(b3Src + (k0), lb + 8192);                      \
    } while (0)

    STAGEW(0, 0);
    STAGEW(1, 32);
    asm volatile("s_waitcnt vmcnt(3)" ::: "memory");
    __builtin_amdgcn_s_barrier();
    __builtin_amdgcn_sched_barrier(0);

    int cur = 0, sb = 2;
    for (int it = 0; it < NIT; ++it) {
        const bool more = (it + 2) < NIT;
        if (more) STAGEW(sb, (it + 2) * 32);
        const bf16* bufA  = LDS + cur * 12288;
        const bf16* bufB1 = bufA + 4096;
        const bf16* bufB3 = bufA + 8192;
        bf16x8 af[4], b1f[2], b3f[2];
#pragma unroll
        for (int i = 0; i < 4; ++i)
            af[i] = *(const bf16x8*)&bufA[(wr * 64 + i * 16 + qr) * 32 + gx8];
#pragma unroll
        for (int j = 0; j < 2; ++j) {
            b1f[j] = *(const bf16x8*)&bufB1[(wc * 32 + j * 16 + qr) * 32 + gx8];
            b3f[j] = *(const bf16x8*)&bufB3[(wc * 32 + j * 16 + qr) * 32 + gx8];
        }
#pragma unroll
        for (int i = 0; i < 4; ++i)
#pragma unroll
            for (int j = 0; j < 2; ++j) {
                acc1[i][j] = MFMA16(b1f[j], af[i], acc1[i][j]);   // swapped
                acc3[i][j] = MFMA16(b3f[j], af[i], acc3[i][j]);   // swapped
            }
        if (more) asm volatile("s_waitcnt vmcnt(3)" ::: "memory");
        else      asm volatile("s_waitcnt vmcnt(0)" ::: "memory");
        __builtin_amdgcn_s_barrier();
        __builtin_amdgcn_sched_barrier(0);
        cur = cur == 2 ? 0 : cur + 1;
        sb  = sb  == 2 ? 0 : sb  + 1;
    }
#undef STAGEW

    // swapped C/D: row = row0+wr*64+i*16+qr, cols = col0+wc*32+j*16+g*4+r
#pragma unroll
    for (int i = 0; i < 4; ++i) {
        const int row = row0 + wr * 64 + i * 16 + qr;
#pragma unroll
        for (int j = 0; j < 2; ++j) {
            const int col = col0 + wc * 32 + j * 16 + g * 4;
            const size_t idx = (size_t)row * N + col;
            bf16 tmp[4];
#pragma unroll
            for (int r = 0; r < 4; ++r) {
                const float u1 = acc1[i][j][r];
                const float u3 = acc3[i][j][r];
                tmp[r] = (bf16)(u1 / (1.f + __expf(-u1)) * u3);
            }
            *(s16x4*)(C + idx) = *(s16x4*)tmp;
        }
    }
}

// ---------------------------------------------------------------------------
// Windowed-ALiBi GQA flash attention (unchanged from round 8: single-barrier
// 3-buffer counted-vmcnt pipeline, swapped QK^T, shfl P^T build).
// ---------------------------------------------------------------------------
__global__ __launch_bounds__(256)
void attn_kernel(const bf16* __restrict__ qn, const bf16* __restrict__ kn,
                 const bf16* __restrict__ vt, bf16* __restrict__ aout) {
    __shared__ bf16 SH[3 * 4096];      // buf: K [32 key][64 hd] | V [64 d][32 key]
    const int t = threadIdx.x, wv = t >> 6, ln = t & 63;
    const int qr = ln & 15, g = ln >> 4;
    const int h = blockIdx.y, b = blockIdx.z, kvh = h >> 1;
    const int q0blk = blockIdx.x * 64;
    const int qa = q0blk + wv * 16 + qr;
    const float slope = exp2f(-0.5f * (float)(h + 1));

    const bf16* qrow = qn + ((size_t)(b * 2048 + qa)) * 1024 + h * 64;
    const bf16x8 qb0 = *(const bf16x8*)(qrow + g * 8);
    const bf16x8 qb1 = *(const bf16x8*)(qrow + 32 + g * 8);

    const bf16* kbase = kn + (size_t)b * 2048 * 512 + kvh * 64;
    const bf16* vbase = vt + ((size_t)(b * 8 + kvh) * 64) * 2048;
    const int krow_l = t >> 3;
    const int kcsrc  = (t & 7) ^ ((t >> 3) & 7);
    const int vd     = t >> 2;
    const int vcsrc  = (t & 3) ^ ((t >> 2) & 3);
    const bf16* kgsrc = kbase + kcsrc * 8;
    const bf16* vgsrc = vbase + (size_t)vd * 2048;
    bf16* lK0 = SH + wv * 512;
    bf16* lV0 = SH + 2048 + wv * 512;

#define STAGE_T(kts, bi)                                           \
    do {                                                           \
        int ksrc = (kts) + krow_l;                                 \
        ksrc = ksrc > 2047 ? 2047 : ksrc;                          \
        gload_lds16(kgsrc + (size_t)ksrc * 512, lK0 + (bi) * 4096);\
        int vsrc = (kts) + vcsrc * 8;                              \
        vsrc = vsrc > 2040 ? 2040 : vsrc;                          \
        gload_lds16(vgsrc + vsrc, lV0 + (bi) * 4096);              \
    } while (0)

    STAGE_T(q0blk, 0);
    STAGE_T(q0blk + 32, 1);
    asm volatile("s_waitcnt vmcnt(2)" ::: "memory");
    __builtin_amdgcn_s_barrier();
    __builtin_amdgcn_sched_barrier(0);

    f32x4 o[4] = {};
    float mrun = -1e29f, lsum = 0.f;
    int cur = 0, sb = 2;

    for (int it = 0; it < 18; ++it) {
        const int kt = q0blk + it * 32;
        const bool more = (it + 2) < 18;
        if (more) STAGE_T(kt + 64, sb);
        const bf16* Kb = SH + cur * 4096;
        const bf16* Vb = Kb + 2048;

        f32x4 sc[2] = {f32x4{0, 0, 0, 0}, f32x4{0, 0, 0, 0}};
#pragma unroll
        for (int ks = 0; ks < 2; ++ks) {
            const int lrow = ks * 16 + qr;
            const int sw = (lrow & 7) * 8;
            sc[ks] = MFMA16(*(const bf16x8*)&Kb[lrow * 64 + (((g) * 8) ^ sw)],        qb0, sc[ks]);
            sc[ks] = MFMA16(*(const bf16x8*)&Kb[lrow * 64 + (((4 + g) * 8) ^ sw)],    qb1, sc[ks]);
        }
        float s[2][4], p[2][4];
        float tmax = -1e30f;
#pragma unroll
        for (int ks = 0; ks < 2; ++ks)
#pragma unroll
            for (int r = 0; r < 4; ++r) {
                const int key = kt + ks * 16 + g * 4 + r;
                const int dist = key - qa;
                const bool valid = (dist >= 0) && (dist <= 512) && (key < 2048);
                const float sv = valid ? sc[ks][r] * 0.125f - slope * (float)dist : -1e30f;
                s[ks][r] = sv;
                tmax = fmaxf(tmax, sv);
            }
        tmax = fmaxf(tmax, __shfl_xor(tmax, 16));
        tmax = fmaxf(tmax, __shfl_xor(tmax, 32));
        const float mnew = fmaxf(mrun, tmax);
        const float alpha = __expf(mrun - mnew);
        mrun = mnew;
        float ps = 0.f;
#pragma unroll
        for (int ks = 0; ks < 2; ++ks)
#pragma unroll
            for (int r = 0; r < 4; ++r) { p[ks][r] = __expf(s[ks][r] - mnew); ps += p[ks][r]; }
        lsum = lsum * alpha + ps;
#pragma unroll
        for (int fd = 0; fd < 4; ++fd) o[fd] *= alpha;

        bf16x8 pb;
#pragma unroll
        for (int j = 0; j < 8; ++j) {
            const int srcl = (((2 * g + (j >> 2)) & 3) << 4) | qr;
            const float v0 = __shfl(p[0][j & 3], srcl);
            const float v1 = __shfl(p[1][j & 3], srcl);
            pb[j] = (bf16)((g & 2) ? v1 : v0);
        }
#pragma unroll
        for (int fd = 0; fd < 4; ++fd) {
            const int d = fd * 16 + qr;
            const bf16x8 va = *(const bf16x8*)&Vb[d * 32 + ((g ^ (d & 3)) * 8)];
            o[fd] = MFMA16(va, pb, o[fd]);
        }

        if (more) asm volatile("s_waitcnt vmcnt(2)" ::: "memory");
        else      asm volatile("s_waitcnt vmcnt(0)" ::: "memory");
        __builtin_amdgcn_s_barrier();
        __builtin_amdgcn_sched_barrier(0);
        cur = cur == 2 ? 0 : cur + 1;
        sb  = sb  == 2 ? 0 : sb  + 1;
    }
#undef STAGE_T

    float lt = lsum + __shfl_xor(lsum, 16);
    lt += __shfl_xor(lt, 32);
    lt = fmaxf(lt, 1e-30f);
    const float inv = 1.f / lt;
    bf16* orow = aout + ((size_t)(b * 2048 + qa)) * 1024 + h * 64;
#pragma unroll
    for (int fd = 0; fd < 4; ++fd) {
        bf16 tmp[4];
#pragma unroll
        for (int r = 0; r < 4; ++r) tmp[r] = (bf16)(o[fd][r] * inv);
        *(s16x4*)(orow + fd * 16 + g * 4) = *(s16x4*)tmp;
    }
}

// ---------------------------------------------------------------------------
extern "C" void kernel_launch(void* const* d_in, const int* in_sizes, int n_in,
                              void* d_out, int out_size, void* d_ws, size_t ws_size,
                              hipStream_t stream) {
    int* flag = (int*)d_ws;
    bf16* base = (bf16*)d_ws + 64;
    bf16* h    = base;                // 4096*1024  (reused as h2)
    bf16* q    = h + 4194304;         // 4096*1024  (x1 after attn)
    bf16* kbuf = q + 4194304;         // 4096*512   (split-K partial base later)
    bf16* vtb  = kbuf + 2097152;      // 2*8*64*2048
    bf16* aout = vtb + 2097152;       // 4096*1024  (kbuf..aout = 2x4194304 span)
    bf16* u    = aout + 4194304;      // 4096*4096  (act)
    bf16* wcv  = u + 16777216;        // 15728640 converted weights (contiguous)

    bf16* woc = wcv + 2097152;
    bf16* w1c = wcv + 3145728;
    bf16* w3c = wcv + 7340032;
    bf16* w2c = wcv + 11534336;

    const dim3 blk(512);
    sniff_kernel<<<1, 256, 0, stream>>>((const unsigned short*)d_in[0], flag);
    convert_all_kernel<<<15360, 256, 0, stream>>>(
        d_in[1], d_in[2], d_in[3], d_in[4], d_in[9], d_in[11], d_in[10], wcv, flag);

    ln_kernel<<<4096, 128, 0, stream>>>(d_in[0], d_in[7], h, 1024, 1e-5f, flag, 1, 1);
    // fused QKV: B = [wq;wk;wv] rows, N=2048.  EPI4: Cout=q, res=kbuf, scale=vtb
    gemm2<4, 3, 0, 0><<<dim3(16, 32), blk, 0, stream>>>(h, wcv, q, kbuf, vtb, 4096, 2048, 1024, flag, 0, 0);
    ln_kernel<<<4096, 128, 0, stream>>>(q, d_in[5], q, 1024, 1e-6f, flag, 0, 1);
    ln_kernel<<<4096, 128, 0, stream>>>(kbuf, d_in[6], kbuf, 512, 1e-6f, flag, 0, 1);
    attn_kernel<<<dim3(32, 16, 2), dim3(256), 0, stream>>>(q, kbuf, vtb, aout);
    // x1 = x + (aout@wo^T)*attn_scale  -> q (bf16)
    gemm2<1, 3, 1, 0><<<dim3(8, 32), blk, 0, stream>>>(aout, woc, q, d_in[0], d_in[12], 4096, 1024, 1024, flag, 1, 0);
    ln_kernel<<<4096, 128, 0, stream>>>(q, d_in[8], h, 1024, 1e-5f, flag, 0, 1);
    // fused SwiGLU up: u = silu(h@w1^T) * (h@w3^T)
    gemm_w13<<<dim3(32, 32), blk, 0, stream>>>(h, w1c, w3c, u, 4096, 4096, 1024);
    // w2 split-K=2: partials (bf16) -> kbuf span, then reduce -> d_out
    gemm2<0, 5, 1, 1><<<dim3(8, 32, 2), blk, 0, stream>>>(u, w2c, kbuf, nullptr, nullptr, 4096, 1024, 4096, flag, 0, 0);
    reduce_k<<<2048, 256, 0, stream>>>(kbuf, q, d_in[13], d_out, flag);
}